// Round 20
// baseline (267.994 us; speedup 1.0000x reference)
//
#include <hip/hip_runtime.h>
#include <type_traits>

// ---------------------------------------------------------------------------
// GPT block forward: B=2, S=2048, D=1024, H=16, DH=64
// Round 20: fc -> gemm256: 256x256 tile, 8 waves, 64 MFMA/wave/barrier-pair.
// Safe coarse 3-step schedule: vmcnt(8)+bar / ds_read-all+lgkm0+bar /
// stage(t+2)+MFMA. All other kernels byte-identical to round 19.
// ---------------------------------------------------------------------------

typedef unsigned short u16;
typedef short s16x8 __attribute__((ext_vector_type(8)));
typedef unsigned short u16x4 __attribute__((ext_vector_type(4)));
typedef float f32x4 __attribute__((ext_vector_type(4)));
typedef float f32x16 __attribute__((ext_vector_type(16)));

__device__ __forceinline__ u16 f2b(float f) {
    union { float f; unsigned u; } x{f};
    unsigned r = x.u + 0x7FFFu + ((x.u >> 16) & 1u);  // RNE
    return (u16)(r >> 16);
}

__device__ __forceinline__ float b2f(u16 v) {
    union { unsigned u; float f; } x;
    x.u = ((unsigned)v) << 16;
    return x.f;
}

__device__ __forceinline__ f32x4 mfma16(s16x8 a, s16x8 b, f32x4 c) {
    return __builtin_amdgcn_mfma_f32_16x16x32_bf16(a, b, c, 0, 0, 0);
}

__device__ __forceinline__ f32x16 mfma32(s16x8 a, s16x8 b, f32x16 c) {
    return __builtin_amdgcn_mfma_f32_32x32x16_bf16(a, b, c, 0, 0, 0);
}

__device__ __forceinline__ int cvtpk(float a, float b) {
    int r;
    asm("v_cvt_pk_bf16_f32 %0, %1, %2" : "=v"(r) : "v"(a), "v"(b));
    return r;
}

__device__ __forceinline__ void gld_lds16(const u16* g, const u16* l) {
    __builtin_amdgcn_global_load_lds(
        (const __attribute__((address_space(1))) void*)g,
        (__attribute__((address_space(3))) void*)l, 16, 0, 0);
}

__device__ __forceinline__ void hard_barrier() {
    __builtin_amdgcn_sched_barrier(0);
    __builtin_amdgcn_s_barrier();
    __builtin_amdgcn_sched_barrier(0);
}

// --------------------------- fp32 -> bf16 convert ---------------------------
__global__ __launch_bounds__(256) void cvt_bf16(const float* __restrict__ in,
                                                u16* __restrict__ out, int n4) {
    int i = blockIdx.x * 256 + threadIdx.x;
    if (i < n4) {
        float4 v = ((const float4*)in)[i];
        u16x4 o = {f2b(v.x), f2b(v.y), f2b(v.z), f2b(v.w)};
        ((u16x4*)out)[i] = o;
    }
}

// ------------------- transpose fp32 [K,N] -> bf16 [N,K] ---------------------
__global__ __launch_bounds__(256) void transpose_bf16(const float* __restrict__ W,
                                                      u16* __restrict__ WT,
                                                      int K, int N) {
    __shared__ float t[32][33];
    int tx = threadIdx.x & 31, ty = threadIdx.x >> 5;
    int n0 = blockIdx.x * 32, k0 = blockIdx.y * 32;
    #pragma unroll
    for (int r = ty; r < 32; r += 8)
        t[r][tx] = W[(size_t)(k0 + r) * N + n0 + tx];
    __syncthreads();
    #pragma unroll
    for (int r = ty; r < 32; r += 8)
        WT[(size_t)(n0 + r) * K + k0 + tx] = f2b(t[tx][r]);
}

// ---------------- gemm256: 256x256 tile, safe 3-step schedule ---------------
// 512 thr = 8 waves (2M x 4N); wave output 128x64; 64 MFMA/wave/K-tile.
// Iter: vmcnt(8)+bar | ds_read all 24 frags -> regs, lgkm0, bar | stage t+2
// into freed buf + 64 reg-only MFMA. Full row&7 granule-XOR swizzle.
// LDS 128 KiB -> 1 block/CU (use only when grid >= 256, i.e. fc).
template<bool GELU, typename OT>
__global__ __launch_bounds__(512) void gemm256(const u16* __restrict__ A,
                                               const u16* __restrict__ BT,
                                               const float* __restrict__ bias,
                                               OT* __restrict__ C,
                                               int M, int N, int K, int ldc) {
    __shared__ u16 As[2][256 * 64];
    __shared__ u16 Bs[2][256 * 64];

    int t = threadIdx.x;
    int w = t >> 6, l = t & 63, l16 = l & 15, lh = l >> 4;
    int wr = w >> 2, wc = w & 3;

    // 2-D XCD chunk: XCD x covers 4 M-tiles x (ntn/2) N-tiles (nbm = 16).
    int id = blockIdx.x;
    int x = id & 7, j = id >> 3;
    int ntn2 = (int)(gridDim.x >> 5);
    int mi = (x & 3) * 4 + (j & 3);
    int ni = (x >> 2) * ntn2 + (j >> 2);
    size_t m0 = (size_t)mi * 256;
    size_t n0 = (size_t)ni * 256;

    // staging: granule g = j*512 + t; row = g>>3 = j*64 + (t>>3); source
    // col-granule pre-XORed with row&7; LDS dest linear (offset 8*g u16).
    int rowA = t >> 3;
    int gc2 = (t & 7) ^ (rowA & 7);
    const u16* Ag = A + (m0 + rowA) * (size_t)K + gc2 * 8;
    const u16* Bg = BT + (n0 + rowA) * (size_t)K + gc2 * 8;
    int t8 = t * 8;

    f32x4 acc[8][4] = {};
    int rx = l16 & 7;                    // read-side granule XOR

#define ST256(KK, BUF)                                                       \
    {                                                                        \
        _Pragma("unroll")                                                    \
        for (int jj = 0; jj < 4; ++jj)                                       \
            gld_lds16(Ag + (KK) + (size_t)(jj * 64) * K,                     \
                      &As[BUF][jj * 4096 + t8]);                             \
        _Pragma("unroll")                                                    \
        for (int jj = 0; jj < 4; ++jj)                                       \
            gld_lds16(Bg + (KK) + (size_t)(jj * 64) * K,                     \
                      &Bs[BUF][jj * 4096 + t8]);                             \
    }

    int NT = K >> 6;
    ST256(0, 0)
    ST256(64, 1)

    #pragma unroll 1
    for (int kt = 0; kt < NT; ++kt) {
        if (kt + 1 < NT) asm volatile("s_waitcnt vmcnt(8)" ::: "memory");
        else             asm volatile("s_waitcnt vmcnt(0)" ::: "memory");
        hard_barrier();                  // buf[kt&1] holds tile kt, all waves

        int cur = kt & 1;
        s16x8 af[8][2], bf[4][2];
        #pragma unroll
        for (int fm = 0; fm < 8; ++fm)
            #pragma unroll
            for (int ks = 0; ks < 2; ++ks) {
                int row = wr * 128 + fm * 16 + l16;
                int col = (((ks * 4 + lh) ^ rx) * 8);
                af[fm][ks] = *(const s16x8*)&As[cur][row * 64 + col];
            }
        #pragma unroll
        for (int fn = 0; fn < 4; ++fn)
            #pragma unroll
            for (int ks = 0; ks < 2; ++ks) {
                int row = wc * 64 + fn * 16 + l16;
                int col = (((ks * 4 + lh) ^ rx) * 8);
                bf[fn][ks] = *(const s16x8*)&Bs[cur][row * 64 + col];
            }
        asm volatile("s_waitcnt lgkmcnt(0)" ::: "memory");
        __builtin_amdgcn_sched_barrier(0);
        hard_barrier();                  // ALL waves consumed buf[cur] -> dead

        if (kt + 2 < NT) ST256((size_t)(kt + 2) * 64, cur)

        __builtin_amdgcn_s_setprio(1);
        #pragma unroll
        for (int fm = 0; fm < 8; ++fm)
            #pragma unroll
            for (int fn = 0; fn < 4; ++fn) {
                acc[fm][fn] = mfma16(af[fm][0], bf[fn][0], acc[fm][fn]);
                acc[fm][fn] = mfma16(af[fm][1], bf[fn][1], acc[fm][fn]);
            }
        __builtin_amdgcn_s_setprio(0);
    }
#undef ST256

    #pragma unroll
    for (int fn = 0; fn < 4; ++fn) {
        size_t col = n0 + wc * 64 + fn * 16 + l16;
        float bs = bias[col];
        #pragma unroll
        for (int fm = 0; fm < 8; ++fm) {
            size_t row0 = m0 + wr * 128 + fm * 16 + lh * 4;
            #pragma unroll
            for (int i = 0; i < 4; ++i) {
                float v = acc[fm][fn][i] + bs;
                if constexpr (GELU) {
                    float x3 = v * v * v;
                    v = 0.5f * v * (1.f + tanhf(0.7978845608f * (v + 0.044715f * x3)));
                }
                if constexpr (std::is_same<OT, u16>::value)
                    C[(row0 + i) * ldc + col] = f2b(v);
                else
                    C[(row0 + i) * ldc + col] = v;
            }
        }
    }
}

// -------- MFMA GEMM, 2-buffer counted-vmcnt, 8 waves on 128xBN tile ---------
template<int BN, bool GELU, typename OT, bool VW = false, bool C2D = false>
__global__ __launch_bounds__(512) void gemm_pl(const u16* __restrict__ A,
                                               const u16* __restrict__ BT,
                                               const float* __restrict__ bias,
                                               OT* __restrict__ C,
                                               u16* __restrict__ vTout,
                                               int M, int N, int K, int ldc) {
    constexpr int NF = BN / 64;
    constexpr int BNI = BN / 64;
    constexpr int LTOT = 2 + BNI;
    __shared__ u16 As[2][128 * 64];
    __shared__ u16 Bs[2][BN * 64];

    int t = threadIdx.x;
    int w = t >> 6, l = t & 63, l16 = l & 15, lh = l >> 4;
    int wr = w >> 2, wc = w & 3;

    int nbm = M >> 7;
    int id = blockIdx.x;
    size_t m0, n0;
    if constexpr (C2D) {
        int x = id & 7, j = id >> 3;
        int ntn2 = (int)(gridDim.x >> 6);
        int mi = (x & 3) * 8 + (j & 7);
        int ni = (x >> 2) * ntn2 + (j >> 3);
        m0 = (size_t)mi * 128;
        n0 = (size_t)ni * BN;
    } else {
        int cpx = gridDim.x >> 3;
        int id2 = (id & 7) * cpx + (id >> 3);
        m0 = (size_t)(id2 % nbm) * 128;
        n0 = (size_t)(id2 / nbm) * BN;
    }

    int rowA = t >> 3;
    int gc2 = (t & 7) ^ (rowA & 7);
    const u16* Ag = A + (m0 + rowA) * (size_t)K + gc2 * 8;
    const u16* Bg = BT + (n0 + rowA) * (size_t)K + gc2 * 8;
    int wb = w * 512;

    f32x4 acc[4][NF] = {};
    int rx = (l16 & 7) * 8;

    #pragma unroll
    for (int j = 0; j < 2; ++j)
        gld_lds16(Ag + (size_t)j * 64 * K, &As[0][j * 4096 + wb]);
    #pragma unroll
    for (int j = 0; j < BNI; ++j)
        gld_lds16(Bg + (size_t)j * 64 * K, &Bs[0][j * 4096 + wb]);
    #pragma unroll
    for (int j = 0; j < 2; ++j)
        gld_lds16(Ag + 64 + (size_t)j * 64 * K, &As[1][j * 4096 + wb]);
    #pragma unroll
    for (int j = 0; j < BNI; ++j)
        gld_lds16(Bg + 64 + (size_t)j * 64 * K, &Bs[1][j * 4096 + wb]);

#define GTILE(CB, kk, LAST)                                                   \
    {                                                                         \
        if (LAST) asm volatile("s_waitcnt vmcnt(0)" ::: "memory");            \
        else      asm volatile("s_waitcnt vmcnt(%0)" :: "n"(LTOT) : "memory");\
        hard_barrier();                                                       \
        __builtin_amdgcn_s_setprio(1);                                        \
        _Pragma("unroll")                                                     \
        for (int ks = 0; ks < 2; ++ks) {                                      \
            s16x8 af[4], bf[NF];                                              \
            _Pragma("unroll")                                                 \
            for (int fm = 0; fm < 4; ++fm) {                                  \
                int row = wr * 64 + fm * 16 + l16;                            \
                int col = ((ks * 4 + lh) * 8) ^ rx;                           \
                af[fm] = *(const s16x8*)&As[CB][row * 64 + col];              \
            }                                                                 \
            _Pragma("unroll")                                                 \
            for (int fn = 0; fn < NF; ++fn) {                                 \
                int row = wc * (BN / 4) + fn * 16 + l16;                      \
                int col = ((ks * 4 + lh) * 8) ^ rx;                           \
                bf[fn] = *(const s16x8*)&Bs[CB][row * 64 + col];              \
            }                                                                 \
            _Pragma("unroll")                                                 \
            for (int fm = 0; fm < 4; ++fm)                                    \
                _Pragma("unroll")                                             \
                for (int fn = 0; fn < NF; ++fn)                               \
                    acc[fm][fn] = mfma16(af[fm], bf[fn], acc[fm][fn]);        \
        }                                                                     \
        __builtin_amdgcn_s_setprio(0);                                        \
        hard_barrier();                                                       \
        if ((kk) + 128 < K) {                                                 \
            const u16* Ap = Ag + (kk) + 128;                                  \
            _Pragma("unroll")                                                 \
            for (int j = 0; j < 2; ++j)                                       \
                gld_lds16(Ap + (size_t)j * 64 * K, &As[CB][j * 4096 + wb]);   \
            const u16* Bp = Bg + (kk) + 128;                                  \
            _Pragma("unroll")                                                 \
            for (int j = 0; j < BNI; ++j)                                     \
                gld_lds16(Bp + (size_t)j * 64 * K, &Bs[CB][j * 4096 + wb]);   \
        }                                                                     \
    }

    for (int k0 = 0; k0 < K; k0 += 128) {
        GTILE(0, k0, (k0 + 64 >= K))
        GTILE(1, k0 + 64, (k0 + 128 >= K))
    }
#undef GTILE

    #pragma unroll
    for (int fn = 0; fn < NF; ++fn) {
        size_t col = n0 + wc * (BN / 4) + fn * 16 + l16;
        float bs = bias[col];
        #pragma unroll
        for (int fm = 0; fm < 4; ++fm) {
            size_t row0 = m0 + wr * 64 + fm * 16 + lh * 4;
            u16x4 pack;
            #pragma unroll
            for (int i = 0; i < 4; ++i) {
                float v = acc[fm][fn][i] + bs;
                if constexpr (GELU) {
                    float x3 = v * v * v;
                    v = 0.5f * v * (1.f + tanhf(0.7978845608f * (v + 0.044715f * x3)));
                }
                if constexpr (std::is_same<OT, u16>::value) {
                    u16 q = f2b(v);
                    C[(row0 + i) * ldc + col] = q;
                    pack[i] = q;
                } else {
                    C[(row0 + i) * ldc + col] = v;
                }
            }
            if constexpr (VW) {
                if (n0 >= 2048) {      // V third (block-uniform)
                    int hh = ((int)col - 2048) >> 6;
                    int dd = ((int)col - 2048) & 63;
                    size_t vrow = (size_t)(((row0 >> 11) * 16 + hh) * 64 + dd);
                    *(u16x4*)(vTout + vrow * 2048 + (row0 & 2047)) = pack;
                }
            }
        }
    }
}

// ---- MFMA GEMM, 3-buffer 2-deep counted-vmcnt, BN=64 (aproj/mproj) ---------
template<bool GELU, typename OT>
__global__ __launch_bounds__(512) void gemm_pl3(const u16* __restrict__ A,
                                                const u16* __restrict__ BT,
                                                const float* __restrict__ bias,
                                                OT* __restrict__ C,
                                                int M, int N, int K, int ldc) {
    __shared__ u16 As[3][128 * 64];
    __shared__ u16 Bs[3][64 * 64];

    int t = threadIdx.x;
    int w = t >> 6, l = t & 63, l16 = l & 15, lh = l >> 4;
    int wr = w >> 2, wc = w & 3;

    int id = blockIdx.x;
    int x = id & 7, j = id >> 3;                 // j in 0..63
    int mi = (x & 3) * 8 + (j & 7);              // 0..31
    int ni = (x >> 2) * 8 + (j >> 3);            // 0..15
    size_t m0 = (size_t)mi * 128;
    size_t n0 = (size_t)ni * 64;

    int rowA = t >> 3;
    int gc2 = (t & 7) ^ (rowA & 7);
    const u16* Ag = A + (m0 + rowA) * (size_t)K + gc2 * 8;
    const u16* Bg = BT + (n0 + rowA) * (size_t)K + gc2 * 8;
    int wb = w * 512;

    f32x4 acc[4] = {};
    int rx = (l16 & 7) * 8;

#define STAGE3(KK, BUF)                                                       \
    {                                                                         \
        gld_lds16(Ag + (KK), &As[BUF][wb]);                                   \
        gld_lds16(Ag + (KK) + (size_t)64 * K, &As[BUF][4096 + wb]);           \
        gld_lds16(Bg + (KK), &Bs[BUF][wb]);                                   \
    }

    int NT = K >> 6;
    STAGE3(0, 0)
    STAGE3(64, 1)
    if (NT > 2) STAGE3(128, 2)

    int cur = 0;
    #pragma unroll 1
    for (int kt = 0; kt < NT; ++kt) {
        if (kt + 2 < NT)      asm volatile("s_waitcnt vmcnt(6)" ::: "memory");
        else if (kt + 1 < NT) asm volatile("s_waitcnt vmcnt(3)" ::: "memory");
        else                  asm volatile("s_waitcnt vmcnt(0)" ::: "memory");
        hard_barrier();

        __builtin_amdgcn_s_setprio(1);
        #pragma unroll
        for (int ks = 0; ks < 2; ++ks) {
            s16x8 af[4], bf;
            #pragma unroll
            for (int fm = 0; fm < 4; ++fm) {
                int row = wr * 64 + fm * 16 + l16;
                int col = ((ks * 4 + lh) * 8) ^ rx;
                af[fm] = *(const s16x8*)&As[cur][row * 64 + col];
            }
            {
                int row = wc * 16 + l16;
                int col = ((ks * 4 + lh) * 8) ^ rx;
                bf = *(const s16x8*)&Bs[cur][row * 64 + col];
            }
            #pragma unroll
            for (int fm = 0; fm < 4; ++fm)
                acc[fm] = mfma16(af[fm], bf, acc[fm]);
        }
        __builtin_amdgcn_s_setprio(0);
        hard_barrier();

        if (kt + 3 < NT) STAGE3((size_t)(kt + 3) * 64, cur)
        cur = (cur == 2) ? 0 : cur + 1;
    }
#undef STAGE3

    size_t col = n0 + wc * 16 + l16;
    float bs = bias[col];
    #pragma unroll
    for (int fm = 0; fm < 4; ++fm) {
        size_t row0 = m0 + wr * 64 + fm * 16 + lh * 4;
        #pragma unroll
        for (int i = 0; i < 4; ++i) {
            float v = acc[fm][i] + bs;
            if constexpr (GELU) {
                float x3 = v * v * v;
                v = 0.5f * v * (1.f + tanhf(0.7978845608f * (v + 0.044715f * x3)));
            }
            if constexpr (std::is_same<OT, u16>::value)
                C[(row0 + i) * ldc + col] = f2b(v);
            else
                C[(row0 + i) * ldc + col] = v;
        }
    }
}

// --------------------------- causal attention -------------------------------
__global__ __launch_bounds__(256) void attn_kernel(const u16* __restrict__ qkv,
                                                   const u16* __restrict__ vT,
                                                   u16* __restrict__ p0,
                                                   u16* __restrict__ p1,
                                                   u16* __restrict__ p2,
                                                   u16* __restrict__ p3,
                                                   float2* __restrict__ stats) {
    constexpr int S = 2048, D3 = 3072, Dm = 1024;
    __shared__ u16 Kl[2][64 * 64];
    __shared__ u16 Vt[2][64 * 64];

    int t = threadIdx.x;
    int w = t >> 6, l = t & 63;
    int l32 = l & 31, hi = l >> 5;
    int bid = blockIdx.x;
    int bh = (bid & 7) * 4 + ((bid >> 3) & 3);
    int rest = bid >> 5;                 // 0..31
    int quar = rest & 3;
    int pr = rest >> 2;                  // 0..7
    int b = bh >> 4, h = bh & 15;
    size_t base = (size_t)b * S * D3;

    u16* pout = quar == 0 ? p0 : (quar == 1 ? p1 : (quar == 2 ? p2 : p3));

    int rK0 = t >> 3, gK = t & 7;
    int rK1 = rK0 + 32;
    size_t koff0 = (size_t)rK0 * D3 + (size_t)((gK ^ (rK0 & 7)) * 8);
    size_t koff1 = (size_t)rK1 * D3 + (size_t)((gK ^ (rK1 & 7)) * 8);
    const u16* kbase = qkv + base + Dm + h * 64;
    size_t voff0 = (size_t)(bh * 64 + rK0) * 2048 + (size_t)((gK ^ (rK0 & 7)) * 8);
    size_t voff1 = (size_t)(bh * 64 + 32 + rK0) * 2048 + (size_t)((gK ^ (rK0 & 7)) * 8);

    constexpr float cexp = 0.18033688011112042f;   // 0.125 * log2(e)
    constexpr float THR = 64.0f;                    // defer-max threshold
    int xg = l32 & 7;

#define STAGE(SC, BUF)                                                        \
    {                                                                         \
        size_t ko_ = (size_t)(SC) * 64 * D3;                                  \
        int kvb_ = (SC) * 64;                                                 \
        gld_lds16(kbase + ko_ + koff0, &Kl[BUF][w * 512]);                    \
        gld_lds16(kbase + ko_ + koff1, &Kl[BUF][2048 + w * 512]);             \
        gld_lds16(vT + voff0 + kvb_, &Vt[BUF][w * 512]);                      \
        gld_lds16(vT + voff1 + kvb_, &Vt[BUF][2048 + w * 512]);               \
    }

    #pragma unroll 1
    for (int ph = 0; ph < 2; ++ph) {
        int qt = ph ? (15 - pr) : pr;
        int qb = qt * 128 + w * 32;
        int nst = 2 * (qt + 1);
        int c0 = (nst * quar) >> 2;
        int c1 = (nst * (quar + 1)) >> 2;

        f32x16 O0 = {}, O1 = {};
        float m = -1e30f, lr = 0.f;

        if (c0 < c1) {
            s16x8 qf[4];
            const u16* qp = qkv + base + (size_t)(qb + l32) * D3 + h * 64 + hi * 8;
            #pragma unroll
            for (int kk = 0; kk < 4; ++kk)
                qf[kk] = *(const s16x8*)(qp + kk * 16);

            STAGE(c0, 0)
            if (c0 + 1 < c1) STAGE(c0 + 1, 1)

            int cur = 0;
            #pragma unroll 1
            for (int sc = c0; sc < c1; ++sc) {
                if (sc + 1 < c1)
                    asm volatile("s_waitcnt vmcnt(4)" ::: "memory");
                else
                    asm volatile("s_waitcnt vmcnt(0)" ::: "memory");
                hard_barrier();

                int kvb = sc * 64;
                int navail = ((qb - kvb) >> 5) + 1;
                if (navail > 0) {
                    if (navail > 2) navail = 2;
                    const u16* Kc = Kl[cur];
                    const u16* Vc = Vt[cur];
                    f32x16 sa0 = {}, sa1 = {};
                    #pragma unroll
                    for (int kk = 0; kk < 4; ++kk) {
                        s16x8 kf = *(const s16x8*)&Kc[l32 * 64 + (((2 * kk + hi) ^ xg) * 8)];
                        sa0 = mfma32(kf, qf[kk], sa0);
                    }
                    if (navail == 2) {
                        #pragma unroll
                        for (int kk = 0; kk < 4; ++kk) {
                            s16x8 kf = *(const s16x8*)&Kc[(32 + l32) * 64 + (((2 * kk + hi) ^ xg) * 8)];
                            sa1 = mfma32(kf, qf[kk], sa1);
                        }
                    }
                    bool diag0 = (kvb == qb);
                    bool diag1 = (kvb + 32 == qb);
                    float p[32];
                    float mx = -1e30f;
                    if (diag0 | diag1) {             // wave-uniform branch
                        #pragma unroll
                        for (int reg = 0; reg < 16; ++reg) {
                            int kvloc = (reg & 3) + 8 * (reg >> 2) + 4 * hi;
                            float s0 = sa0[reg];
                            if (diag0 && kvloc > l32) s0 = -1e30f;
                            p[reg] = s0;
                            mx = fmaxf(mx, s0);
                        }
                        if (navail == 2) {
                            #pragma unroll
                            for (int reg = 0; reg < 16; ++reg) {
                                int kvloc = (reg & 3) + 8 * (reg >> 2) + 4 * hi;
                                float s1 = sa1[reg];
                                if (diag1 && kvloc > l32) s1 = -1e30f;
                                p[16 + reg] = s1;
                                mx = fmaxf(mx, s1);
                            }
                        }
                    } else {
                        #pragma unroll
                        for (int reg = 0; reg < 16; ++reg) {
                            p[reg] = sa0[reg];
                            mx = fmaxf(mx, sa0[reg]);
                        }
                        if (navail == 2) {
                            #pragma unroll
                            for (int reg = 0; reg < 16; ++reg) {
                                p[16 + reg] = sa1[reg];
                                mx = fmaxf(mx, sa1[reg]);
                            }
                        }
                    }
                    mx = fmaxf(mx, __shfl_xor(mx, 32));
                    if (!__all(mx <= m + THR)) {          // defer-max (T13)
                        float mn = fmaxf(m, mx);
                        float a_ = exp2f(cexp * (m - mn));
                        m = mn;
                        #pragma unroll
                        for (int reg = 0; reg < 16; ++reg) {
                            int src = (reg & 3) + 8 * (reg >> 2) + 4 * hi;
                            float aq = __shfl(a_, src);
                            O0[reg] *= aq;
                            O1[reg] *= aq;
                        }
                        lr *= a_;
                    }
                    float cm = cexp * m;
                    float rs = 0.f;
                    #pragma unroll
                    for (int reg = 0; reg < 16; ++reg) {
                        p[reg] = exp2f(fmaf(cexp, p[reg], -cm));
                        rs += p[reg];
                    }
                    if (navail == 2) {
                        #pragma unroll
                        for (int reg = 16; reg < 32; ++reg) {
                            p[reg] = exp2f(fmaf(cexp, p[reg], -cm));
                            rs += p[reg];
                        }
                    }
                    rs += __shfl_xor(rs, 32);
                    lr += rs;

                    #pragma unroll
                    for (int c = 0; c < 4; ++c) {
                        if (c < navail * 2) {
                            int pb = (c >> 1) * 16 + (c & 1) * 8;
                            int pk01 = cvtpk(p[pb + 0], p[pb + 1]);
                            int pk23 = cvtpk(p[pb + 2], p[pb + 3]);
                            int pk45 = cvtpk(p[pb + 4], p[pb + 5]);
                            int pk67 = cvtpk(p[pb + 6], p[pb + 7]);
                            int sx01 = __shfl_xor(pk01, 32);
                            int sx23 = __shfl_xor(pk23, 32);
                            int sx45 = __shfl_xor(pk45, 32);
                            int sx67 = __shfl_xor(pk67, 32);
                            union { int i[4]; s16x8 v; } u;
                            u.i[0] = hi ? sx45 : pk01;
                            u.i[1] = hi ? sx67 : pk23;
                            u.i[2] = hi ? pk45 : sx01;
                            u.i[3] = hi ? pk67 : sx23;
                            int go = ((c * 2 + hi) ^ xg) * 8;
                            s16x8 vb0 = *(const s16x8*)&Vc[l32 * 64 + go];
                            O0 = mfma32(u.v, vb0, O0);
                            s16x8 vb1 = *(const s16x8*)&Vc[(32 + l32) * 64 + go];
                            O1 = mfma32(u.v, vb1, O1);
                        }
                    }
                }

                hard_barrier();
                if (sc + 2 < c1) STAGE(sc + 2, cur)
                cur ^= 1;
            }
        }

        size_t obase = (size_t)b * S * 1024 + h * 64;
        #pragma unroll
        for (int reg = 0; reg < 16; ++reg) {
            int src = (reg & 3) + 8 * (reg >> 2) + 4 * hi;
            size_t row = obase + (size_t)(qb + src) * 1024;
            pout[row + l32] = f2b(O0[reg]);
            pout[row + 32 + l32] = f2b(O1[reg]);
        }
        if (hi == 0) {
            float2 st; st.x = m; st.y = lr;
            stats[quar * 65536 + ((b * 2048 + qb + l32) * 16 + h)] = st;
        }
    }
#undef STAGE
}

// ------------------------- attention partial merge (x4) ---------------------
__global__ __launch_bounds__(256) void merge_attn(u16* __restrict__ p0,
                                                  const u16* __restrict__ p1,
                                                  const u16* __restrict__ p2,
                                                  const u16* __restrict__ p3,
                                                  const float2* __restrict__ stats) {
    constexpr float cexp = 0.18033688011112042f;
    int gid = blockIdx.x * 256 + threadIdx.x;    // [0, 65536*4)
    int rh = gid >> 2;
    int dc = (gid & 3) * 16;
    int R = rh >> 4, h = rh & 15;
    size_t addr = (size_t)R * 1024 + h * 64 + dc;

    float2 s0 = stats[rh];
    float2 s1 = stats[65536 + rh];
    float2 s2 = stats[131072 + rh];
    float2 s3 = stats[196608 + rh];
    float M = fmaxf(fmaxf(s0.x, s1.x), fmaxf(s2.x, s3.x));
    float a0 = exp2f(cexp * (s0.x - M));
    float a1 = exp2f(cexp * (s1.x - M));
    float a2 = exp2f(cexp * (s2.x - M));
    float a3 = exp2f(cexp * (s3.x - M));
    float inv = 1.f / (a0 * s0.y + a1 * s1.y + a2 * s2.y + a3 * s3.y);
    a0 *= inv; a1 *= inv; a2 *= inv; a3 *= inv;

    u16x4 o[4];
    #pragma unroll
    for (int j = 0; j < 4; ++j) {
        u16x4 q0 = *(const u16x4*)(p0 + addr + j * 4);
        u16x4 q1 = *(const u16x4*)(p1 + addr + j * 4);
        u16x4 q2 = *(const u16x4*)(p2 + addr + j * 4);
        u16x4 q3 = *(const u16x4*)(p3 + addr + j * 4);
        #pragma unroll
        for (int e = 0; e < 4; ++e)
            o[j][e] = f2b(a0 * b2f(q0[e]) + a1 * b2f(q1[e]) +
                          a2 * b2f(q2[e]) + a3 * b2f(q3[e]));
    }
    #pragma unroll
    for (int j = 0; j < 4; ++j)
        *(u16x4*)(p0 + addr + j * 4) = o[j];
}

// --------------------- residual + LayerNorm (row = 1024) --------------------
template<bool WB>
__global__ __launch_bounds__(256) void resln(const float* __restrict__ xa,
                                             const float* __restrict__ xb2,
                                             const float* __restrict__ g,
                                             const float* __restrict__ be,
                                             float* __restrict__ outf,
                                             u16* __restrict__ outb) {
    int row = blockIdx.x;
    int t = threadIdx.x;
    size_t base = (size_t)row * 1024 + t * 4;
    float4 va = *(const float4*)(xa + base);
    float4 vb = *(const float4*)(xb2 + base);
    float v0 = va.x + vb.x, v1 = va.y + vb.y, v2 = va.z + vb.z, v3 = va.w + vb.w;
    float s1 = v0 + v1 + v2 + v3;
    float s2 = v0 * v0 + v1 * v1 + v2 * v2 + v3 * v3;
    #pragma unroll
    for (int off = 32; off >= 1; off >>= 1) {
        s1 += __shfl_down(s1, off);
        s2 += __shfl_down(s2, off);
    }
    __shared__ float r1[4], r2[4];
    if ((t & 63) == 0) { r1[t >> 6] = s1; r2[t >> 6] = s2; }
    __syncthreads();
    s1 = r1[0] + r1[1] + r1[2] + r1[3];
    s2 = r2[0] + r2[1] + r2[2] + r2[3];
    float mean = s1 * (1.f / 1024.f);
    float var = fmaxf((s2 - 1024.f * mean * mean) * (1.f / 1023.f), 0.f);
    float inv = 1.f / (sqrtf(var) + 1e-6f);
    int col = t * 4;
    float y0 = g[col + 0] * ((v0 - mean) * inv) + be[col + 0];
    float y1 = g[col + 1] * ((v1 - mean) * inv) + be[col + 1];
    float y2 = g[col + 2] * ((v2 - mean) * inv) + be[col + 2];
    float y3 = g[col + 3] * ((v3 - mean) * inv) + be[col + 3];
    float4 o = {y0, y1, y2, y3};
    *(float4*)(outf + base) = o;
    if constexpr (WB) {
        u16x4 ob = {f2b(y0), f2b(y1), f2b(y2), f2b(y3)};
        *(u16x4*)(outb + base) = ob;
    }
}

// ---------------------------------------------------------------------------
extern "C" void kernel_launch(void* const* d_in, const int* in_sizes, int n_in,
                              void* d_out, int out_size, void* d_ws, size_t ws_size,
                              hipStream_t stream) {
    (void)in_sizes; (void)n_in; (void)out_size; (void)ws_size;
    const float* x       = (const float*)d_in[0];
    const float* w_attn  = (const float*)d_in[1];
    const float* b_attn  = (const float*)d_in[2];
    const float* w_aproj = (const float*)d_in[3];
    const float* b_aproj = (const float*)d_in[4];
    const float* g1      = (const float*)d_in[5];
    const float* b1      = (const float*)d_in[6];
    const float* w_fc    = (const float*)d_in[7];
    const float* b_fc    = (const float*)d_in[8];
    const float* w_mproj = (const float*)d_in[9];
    const float* b_mproj = (const float*)d_in[10];
    const float* g2      = (const float*)d_in[11];
    const float* b2      = (const float*)d_in[12];
    float* out = (float*)d_out;

    constexpr int M = 4096;           // B*S
    constexpr int D = 1024;

    char* ws = (char*)d_ws;
    u16*   slotA = (u16*)ws;                         // 32 MiB: qkv(24)+vT(8) -> h
    char*  pB    = ws + (32u << 20);                 //  8 MiB: xb -> part0/abuf -> nb
    char*  pC    = ws + (40u << 20);                 //  8 MiB: part1 -> wT
    char*  pD    = ws + (48u << 20);                 // 16 MiB: part2+part3 -> aout -> mout
    char*  pE    = ws + (64u << 20);                 // 16 MiB: stats -> nbuf (fp32)

    u16*   xb    = (u16*)pB;
    u16*   wT    = (u16*)pC;
    u16*   qkv   = slotA;
    u16*   vT    = slotA + (24u << 20) / 2;          // 8 MiB region after qkv
    u16*   part0 = (u16*)pB;                         // becomes merged abuf
    u16*   part1 = (u16*)pC;
    u16*   part2 = (u16*)pD;
    u16*   part3 = (u16*)(pD + (8u << 20));
    float2* stat = (float2*)pE;
    u16*   abuf  = (u16*)pB;
    float* aout  = (float*)pD;
    float* nbuf  = (float*)pE;
    u16*   nb    = (u16*)pB;
    u16*   h     = slotA;
    float* mout  = (float*)pD;

    dim3 blk(256);
    dim3 blk512(512);

    cvt_bf16<<<dim3(4096), blk, 0, stream>>>(x, xb, M * D / 4);

    transpose_bf16<<<dim3(3072 / 32, 1024 / 32), blk, 0, stream>>>(w_attn, wT, 1024, 3072);
    gemm_pl<128, false, u16, true><<<dim3((M / 128) * (3072 / 128)), blk512, 0, stream>>>(
        xb, wT, b_attn, qkv, vT, M, 3072, 1024, 3072);

    attn_kernel<<<dim3(1024), blk, 0, stream>>>(qkv, vT, part0, part1, part2, part3, stat);
    merge_attn<<<dim3(1024), blk, 0, stream>>>(part0, part1, part2, part3, stat);

    transpose_bf16<<<dim3(1024 / 32, 1024 / 32), blk, 0, stream>>>(w_aproj, wT, 1024, 1024);
    gemm_pl3<false, float><<<dim3((M / 128) * (1024 / 64)), blk512, 0, stream>>>(
        abuf, wT, b_aproj, aout, M, 1024, 1024, 1024);

    resln<true><<<dim3(M), blk, 0, stream>>>(x, aout, g1, b1, nbuf, nb);

    transpose_bf16<<<dim3(4096 / 32, 1024 / 32), blk, 0, stream>>>(w_fc, wT, 1024, 4096);
    gemm256<true, u16><<<dim3((M / 256) * (4096 / 256)), blk512, 0, stream>>>(
        nb, wT, b_fc, h, M, 4096, 1024, 4096);

    transpose_bf16<<<dim3(1024 / 32, 4096 / 32), blk, 0, stream>>>(w_mproj, wT, 4096, 1024);
    gemm_pl3<false, float><<<dim3((M / 128) * (1024 / 64)), blk512, 0, stream>>>(
        h, wT, b_mproj, mout, M, 1024, 4096, 1024);

    resln<false><<<dim3(M), blk, 0, stream>>>(nbuf, mout, g2, b2, out, nullptr);
}

// Round 21
// 265.802 us; speedup vs baseline: 1.0082x; 1.0082x over previous
//
#include <hip/hip_runtime.h>
#include <type_traits>

// ---------------------------------------------------------------------------
// GPT block forward: B=2, S=2048, D=1024, H=16, DH=64
// Round 21: revert to round-19 best (265.5 us): gemm256 experiment regressed
// (1 block/CU lockstep, MfmaUtil 19%). fc = gemm_pl<128,C2D>; qkv =
// gemm_pl<128,VW>; aproj/mproj = gemm_pl3; attention kv-split x4 + fused vT.
// ---------------------------------------------------------------------------

typedef unsigned short u16;
typedef short s16x8 __attribute__((ext_vector_type(8)));
typedef unsigned short u16x4 __attribute__((ext_vector_type(4)));
typedef float f32x4 __attribute__((ext_vector_type(4)));
typedef float f32x16 __attribute__((ext_vector_type(16)));

__device__ __forceinline__ u16 f2b(float f) {
    union { float f; unsigned u; } x{f};
    unsigned r = x.u + 0x7FFFu + ((x.u >> 16) & 1u);  // RNE
    return (u16)(r >> 16);
}

__device__ __forceinline__ float b2f(u16 v) {
    union { unsigned u; float f; } x;
    x.u = ((unsigned)v) << 16;
    return x.f;
}

__device__ __forceinline__ f32x4 mfma16(s16x8 a, s16x8 b, f32x4 c) {
    return __builtin_amdgcn_mfma_f32_16x16x32_bf16(a, b, c, 0, 0, 0);
}

__device__ __forceinline__ f32x16 mfma32(s16x8 a, s16x8 b, f32x16 c) {
    return __builtin_amdgcn_mfma_f32_32x32x16_bf16(a, b, c, 0, 0, 0);
}

__device__ __forceinline__ int cvtpk(float a, float b) {
    int r;
    asm("v_cvt_pk_bf16_f32 %0, %1, %2" : "=v"(r) : "v"(a), "v"(b));
    return r;
}

__device__ __forceinline__ void gld_lds16(const u16* g, const u16* l) {
    __builtin_amdgcn_global_load_lds(
        (const __attribute__((address_space(1))) void*)g,
        (__attribute__((address_space(3))) void*)l, 16, 0, 0);
}

__device__ __forceinline__ void hard_barrier() {
    __builtin_amdgcn_sched_barrier(0);
    __builtin_amdgcn_s_barrier();
    __builtin_amdgcn_sched_barrier(0);
}

// --------------------------- fp32 -> bf16 convert ---------------------------
__global__ __launch_bounds__(256) void cvt_bf16(const float* __restrict__ in,
                                                u16* __restrict__ out, int n4) {
    int i = blockIdx.x * 256 + threadIdx.x;
    if (i < n4) {
        float4 v = ((const float4*)in)[i];
        u16x4 o = {f2b(v.x), f2b(v.y), f2b(v.z), f2b(v.w)};
        ((u16x4*)out)[i] = o;
    }
}

// ------------------- transpose fp32 [K,N] -> bf16 [N,K] ---------------------
__global__ __launch_bounds__(256) void transpose_bf16(const float* __restrict__ W,
                                                      u16* __restrict__ WT,
                                                      int K, int N) {
    __shared__ float t[32][33];
    int tx = threadIdx.x & 31, ty = threadIdx.x >> 5;
    int n0 = blockIdx.x * 32, k0 = blockIdx.y * 32;
    #pragma unroll
    for (int r = ty; r < 32; r += 8)
        t[r][tx] = W[(size_t)(k0 + r) * N + n0 + tx];
    __syncthreads();
    #pragma unroll
    for (int r = ty; r < 32; r += 8)
        WT[(size_t)(n0 + r) * K + k0 + tx] = f2b(t[tx][r]);
}

// -------- MFMA GEMM, 2-buffer counted-vmcnt, 8 waves on 128xBN tile ---------
// VW: qkv V-third blocks also write transposed vT. C2D: 2-D XCD chunk.
template<int BN, bool GELU, typename OT, bool VW = false, bool C2D = false>
__global__ __launch_bounds__(512) void gemm_pl(const u16* __restrict__ A,
                                               const u16* __restrict__ BT,
                                               const float* __restrict__ bias,
                                               OT* __restrict__ C,
                                               u16* __restrict__ vTout,
                                               int M, int N, int K, int ldc) {
    constexpr int NF = BN / 64;
    constexpr int BNI = BN / 64;
    constexpr int LTOT = 2 + BNI;
    __shared__ u16 As[2][128 * 64];
    __shared__ u16 Bs[2][BN * 64];

    int t = threadIdx.x;
    int w = t >> 6, l = t & 63, l16 = l & 15, lh = l >> 4;
    int wr = w >> 2, wc = w & 3;

    int nbm = M >> 7;
    int id = blockIdx.x;
    size_t m0, n0;
    if constexpr (C2D) {
        int x = id & 7, j = id >> 3;
        int ntn2 = (int)(gridDim.x >> 6);
        int mi = (x & 3) * 8 + (j & 7);
        int ni = (x >> 2) * ntn2 + (j >> 3);
        m0 = (size_t)mi * 128;
        n0 = (size_t)ni * BN;
    } else {
        int cpx = gridDim.x >> 3;
        int id2 = (id & 7) * cpx + (id >> 3);
        m0 = (size_t)(id2 % nbm) * 128;
        n0 = (size_t)(id2 / nbm) * BN;
    }

    int rowA = t >> 3;
    int gc2 = (t & 7) ^ (rowA & 7);
    const u16* Ag = A + (m0 + rowA) * (size_t)K + gc2 * 8;
    const u16* Bg = BT + (n0 + rowA) * (size_t)K + gc2 * 8;
    int wb = w * 512;

    f32x4 acc[4][NF] = {};
    int rx = (l16 & 7) * 8;

    #pragma unroll
    for (int j = 0; j < 2; ++j)
        gld_lds16(Ag + (size_t)j * 64 * K, &As[0][j * 4096 + wb]);
    #pragma unroll
    for (int j = 0; j < BNI; ++j)
        gld_lds16(Bg + (size_t)j * 64 * K, &Bs[0][j * 4096 + wb]);
    #pragma unroll
    for (int j = 0; j < 2; ++j)
        gld_lds16(Ag + 64 + (size_t)j * 64 * K, &As[1][j * 4096 + wb]);
    #pragma unroll
    for (int j = 0; j < BNI; ++j)
        gld_lds16(Bg + 64 + (size_t)j * 64 * K, &Bs[1][j * 4096 + wb]);

#define GTILE(CB, kk, LAST)                                                   \
    {                                                                         \
        if (LAST) asm volatile("s_waitcnt vmcnt(0)" ::: "memory");            \
        else      asm volatile("s_waitcnt vmcnt(%0)" :: "n"(LTOT) : "memory");\
        hard_barrier();                                                       \
        __builtin_amdgcn_s_setprio(1);                                        \
        _Pragma("unroll")                                                     \
        for (int ks = 0; ks < 2; ++ks) {                                      \
            s16x8 af[4], bf[NF];                                              \
            _Pragma("unroll")                                                 \
            for (int fm = 0; fm < 4; ++fm) {                                  \
                int row = wr * 64 + fm * 16 + l16;                            \
                int col = ((ks * 4 + lh) * 8) ^ rx;                           \
                af[fm] = *(const s16x8*)&As[CB][row * 64 + col];              \
            }                                                                 \
            _Pragma("unroll")                                                 \
            for (int fn = 0; fn < NF; ++fn) {                                 \
                int row = wc * (BN / 4) + fn * 16 + l16;                      \
                int col = ((ks * 4 + lh) * 8) ^ rx;                           \
                bf[fn] = *(const s16x8*)&Bs[CB][row * 64 + col];              \
            }                                                                 \
            _Pragma("unroll")                                                 \
            for (int fm = 0; fm < 4; ++fm)                                    \
                _Pragma("unroll")                                             \
                for (int fn = 0; fn < NF; ++fn)                               \
                    acc[fm][fn] = mfma16(af[fm], bf[fn], acc[fm][fn]);        \
        }                                                                     \
        __builtin_amdgcn_s_setprio(0);                                        \
        hard_barrier();                                                       \
        if ((kk) + 128 < K) {                                                 \
            const u16* Ap = Ag + (kk) + 128;                                  \
            _Pragma("unroll")                                                 \
            for (int j = 0; j < 2; ++j)                                       \
                gld_lds16(Ap + (size_t)j * 64 * K, &As[CB][j * 4096 + wb]);   \
            const u16* Bp = Bg + (kk) + 128;                                  \
            _Pragma("unroll")                                                 \
            for (int j = 0; j < BNI; ++j)                                     \
                gld_lds16(Bp + (size_t)j * 64 * K, &Bs[CB][j * 4096 + wb]);   \
        }                                                                     \
    }

    for (int k0 = 0; k0 < K; k0 += 128) {
        GTILE(0, k0, (k0 + 64 >= K))
        GTILE(1, k0 + 64, (k0 + 128 >= K))
    }
#undef GTILE

    #pragma unroll
    for (int fn = 0; fn < NF; ++fn) {
        size_t col = n0 + wc * (BN / 4) + fn * 16 + l16;
        float bs = bias[col];
        #pragma unroll
        for (int fm = 0; fm < 4; ++fm) {
            size_t row0 = m0 + wr * 64 + fm * 16 + lh * 4;
            u16x4 pack;
            #pragma unroll
            for (int i = 0; i < 4; ++i) {
                float v = acc[fm][fn][i] + bs;
                if constexpr (GELU) {
                    float x3 = v * v * v;
                    v = 0.5f * v * (1.f + tanhf(0.7978845608f * (v + 0.044715f * x3)));
                }
                if constexpr (std::is_same<OT, u16>::value) {
                    u16 q = f2b(v);
                    C[(row0 + i) * ldc + col] = q;
                    pack[i] = q;
                } else {
                    C[(row0 + i) * ldc + col] = v;
                }
            }
            if constexpr (VW) {
                if (n0 >= 2048) {      // V third (block-uniform)
                    int hh = ((int)col - 2048) >> 6;
                    int dd = ((int)col - 2048) & 63;
                    size_t vrow = (size_t)(((row0 >> 11) * 16 + hh) * 64 + dd);
                    *(u16x4*)(vTout + vrow * 2048 + (row0 & 2047)) = pack;
                }
            }
        }
    }
}

// ---- MFMA GEMM, 3-buffer 2-deep counted-vmcnt, BN=64 (aproj/mproj) ---------
template<bool GELU, typename OT>
__global__ __launch_bounds__(512) void gemm_pl3(const u16* __restrict__ A,
                                                const u16* __restrict__ BT,
                                                const float* __restrict__ bias,
                                                OT* __restrict__ C,
                                                int M, int N, int K, int ldc) {
    __shared__ u16 As[3][128 * 64];
    __shared__ u16 Bs[3][64 * 64];

    int t = threadIdx.x;
    int w = t >> 6, l = t & 63, l16 = l & 15, lh = l >> 4;
    int wr = w >> 2, wc = w & 3;

    int id = blockIdx.x;
    int x = id & 7, j = id >> 3;                 // j in 0..63
    int mi = (x & 3) * 8 + (j & 7);              // 0..31
    int ni = (x >> 2) * 8 + (j >> 3);            // 0..15
    size_t m0 = (size_t)mi * 128;
    size_t n0 = (size_t)ni * 64;

    int rowA = t >> 3;
    int gc2 = (t & 7) ^ (rowA & 7);
    const u16* Ag = A + (m0 + rowA) * (size_t)K + gc2 * 8;
    const u16* Bg = BT + (n0 + rowA) * (size_t)K + gc2 * 8;
    int wb = w * 512;

    f32x4 acc[4] = {};
    int rx = (l16 & 7) * 8;

#define STAGE3(KK, BUF)                                                       \
    {                                                                         \
        gld_lds16(Ag + (KK), &As[BUF][wb]);                                   \
        gld_lds16(Ag + (KK) + (size_t)64 * K, &As[BUF][4096 + wb]);           \
        gld_lds16(Bg + (KK), &Bs[BUF][wb]);                                   \
    }

    int NT = K >> 6;
    STAGE3(0, 0)
    STAGE3(64, 1)
    if (NT > 2) STAGE3(128, 2)

    int cur = 0;
    #pragma unroll 1
    for (int kt = 0; kt < NT; ++kt) {
        if (kt + 2 < NT)      asm volatile("s_waitcnt vmcnt(6)" ::: "memory");
        else if (kt + 1 < NT) asm volatile("s_waitcnt vmcnt(3)" ::: "memory");
        else                  asm volatile("s_waitcnt vmcnt(0)" ::: "memory");
        hard_barrier();

        __builtin_amdgcn_s_setprio(1);
        #pragma unroll
        for (int ks = 0; ks < 2; ++ks) {
            s16x8 af[4], bf;
            #pragma unroll
            for (int fm = 0; fm < 4; ++fm) {
                int row = wr * 64 + fm * 16 + l16;
                int col = ((ks * 4 + lh) * 8) ^ rx;
                af[fm] = *(const s16x8*)&As[cur][row * 64 + col];
            }
            {
                int row = wc * 16 + l16;
                int col = ((ks * 4 + lh) * 8) ^ rx;
                bf = *(const s16x8*)&Bs[cur][row * 64 + col];
            }
            #pragma unroll
            for (int fm = 0; fm < 4; ++fm)
                acc[fm] = mfma16(af[fm], bf, acc[fm]);
        }
        __builtin_amdgcn_s_setprio(0);
        hard_barrier();

        if (kt + 3 < NT) STAGE3((size_t)(kt + 3) * 64, cur)
        cur = (cur == 2) ? 0 : cur + 1;
    }
#undef STAGE3

    size_t col = n0 + wc * 16 + l16;
    float bs = bias[col];
    #pragma unroll
    for (int fm = 0; fm < 4; ++fm) {
        size_t row0 = m0 + wr * 64 + fm * 16 + lh * 4;
        #pragma unroll
        for (int i = 0; i < 4; ++i) {
            float v = acc[fm][i] + bs;
            if constexpr (GELU) {
                float x3 = v * v * v;
                v = 0.5f * v * (1.f + tanhf(0.7978845608f * (v + 0.044715f * x3)));
            }
            if constexpr (std::is_same<OT, u16>::value)
                C[(row0 + i) * ldc + col] = f2b(v);
            else
                C[(row0 + i) * ldc + col] = v;
        }
    }
}

// --------------------------- causal attention -------------------------------
__global__ __launch_bounds__(256) void attn_kernel(const u16* __restrict__ qkv,
                                                   const u16* __restrict__ vT,
                                                   u16* __restrict__ p0,
                                                   u16* __restrict__ p1,
                                                   u16* __restrict__ p2,
                                                   u16* __restrict__ p3,
                                                   float2* __restrict__ stats) {
    constexpr int S = 2048, D3 = 3072, Dm = 1024;
    __shared__ u16 Kl[2][64 * 64];
    __shared__ u16 Vt[2][64 * 64];

    int t = threadIdx.x;
    int w = t >> 6, l = t & 63;
    int l32 = l & 31, hi = l >> 5;
    int bid = blockIdx.x;
    int bh = (bid & 7) * 4 + ((bid >> 3) & 3);
    int rest = bid >> 5;                 // 0..31
    int quar = rest & 3;
    int pr = rest >> 2;                  // 0..7
    int b = bh >> 4, h = bh & 15;
    size_t base = (size_t)b * S * D3;

    u16* pout = quar == 0 ? p0 : (quar == 1 ? p1 : (quar == 2 ? p2 : p3));

    int rK0 = t >> 3, gK = t & 7;
    int rK1 = rK0 + 32;
    size_t koff0 = (size_t)rK0 * D3 + (size_t)((gK ^ (rK0 & 7)) * 8);
    size_t koff1 = (size_t)rK1 * D3 + (size_t)((gK ^ (rK1 & 7)) * 8);
    const u16* kbase = qkv + base + Dm + h * 64;
    size_t voff0 = (size_t)(bh * 64 + rK0) * 2048 + (size_t)((gK ^ (rK0 & 7)) * 8);
    size_t voff1 = (size_t)(bh * 64 + 32 + rK0) * 2048 + (size_t)((gK ^ (rK0 & 7)) * 8);

    constexpr float cexp = 0.18033688011112042f;   // 0.125 * log2(e)
    constexpr float THR = 64.0f;                    // defer-max threshold
    int xg = l32 & 7;

#define STAGE(SC, BUF)                                                        \
    {                                                                         \
        size_t ko_ = (size_t)(SC) * 64 * D3;                                  \
        int kvb_ = (SC) * 64;                                                 \
        gld_lds16(kbase + ko_ + koff0, &Kl[BUF][w * 512]);                    \
        gld_lds16(kbase + ko_ + koff1, &Kl[BUF][2048 + w * 512]);             \
        gld_lds16(vT + voff0 + kvb_, &Vt[BUF][w * 512]);                      \
        gld_lds16(vT + voff1 + kvb_, &Vt[BUF][2048 + w * 512]);               \
    }

    #pragma unroll 1
    for (int ph = 0; ph < 2; ++ph) {
        int qt = ph ? (15 - pr) : pr;
        int qb = qt * 128 + w * 32;
        int nst = 2 * (qt + 1);
        int c0 = (nst * quar) >> 2;
        int c1 = (nst * (quar + 1)) >> 2;

        f32x16 O0 = {}, O1 = {};
        float m = -1e30f, lr = 0.f;

        if (c0 < c1) {
            s16x8 qf[4];
            const u16* qp = qkv + base + (size_t)(qb + l32) * D3 + h * 64 + hi * 8;
            #pragma unroll
            for (int kk = 0; kk < 4; ++kk)
                qf[kk] = *(const s16x8*)(qp + kk * 16);

            STAGE(c0, 0)
            if (c0 + 1 < c1) STAGE(c0 + 1, 1)

            int cur = 0;
            #pragma unroll 1
            for (int sc = c0; sc < c1; ++sc) {
                if (sc + 1 < c1)
                    asm volatile("s_waitcnt vmcnt(4)" ::: "memory");
                else
                    asm volatile("s_waitcnt vmcnt(0)" ::: "memory");
                hard_barrier();

                int kvb = sc * 64;
                int navail = ((qb - kvb) >> 5) + 1;
                if (navail > 0) {
                    if (navail > 2) navail = 2;
                    const u16* Kc = Kl[cur];
                    const u16* Vc = Vt[cur];
                    f32x16 sa0 = {}, sa1 = {};
                    #pragma unroll
                    for (int kk = 0; kk < 4; ++kk) {
                        s16x8 kf = *(const s16x8*)&Kc[l32 * 64 + (((2 * kk + hi) ^ xg) * 8)];
                        sa0 = mfma32(kf, qf[kk], sa0);
                    }
                    if (navail == 2) {
                        #pragma unroll
                        for (int kk = 0; kk < 4; ++kk) {
                            s16x8 kf = *(const s16x8*)&Kc[(32 + l32) * 64 + (((2 * kk + hi) ^ xg) * 8)];
                            sa1 = mfma32(kf, qf[kk], sa1);
                        }
                    }
                    bool diag0 = (kvb == qb);
                    bool diag1 = (kvb + 32 == qb);
                    float p[32];
                    float mx = -1e30f;
                    if (diag0 | diag1) {             // wave-uniform branch
                        #pragma unroll
                        for (int reg = 0; reg < 16; ++reg) {
                            int kvloc = (reg & 3) + 8 * (reg >> 2) + 4 * hi;
                            float s0 = sa0[reg];
                            if (diag0 && kvloc > l32) s0 = -1e30f;
                            p[reg] = s0;
                            mx = fmaxf(mx, s0);
                        }
                        if (navail == 2) {
                            #pragma unroll
                            for (int reg = 0; reg < 16; ++reg) {
                                int kvloc = (reg & 3) + 8 * (reg >> 2) + 4 * hi;
                                float s1 = sa1[reg];
                                if (diag1 && kvloc > l32) s1 = -1e30f;
                                p[16 + reg] = s1;
                                mx = fmaxf(mx, s1);
                            }
                        }
                    } else {
                        #pragma unroll
                        for (int reg = 0; reg < 16; ++reg) {
                            p[reg] = sa0[reg];
                            mx = fmaxf(mx, sa0[reg]);
                        }
                        if (navail == 2) {
                            #pragma unroll
                            for (int reg = 0; reg < 16; ++reg) {
                                p[16 + reg] = sa1[reg];
                                mx = fmaxf(mx, sa1[reg]);
                            }
                        }
                    }
                    mx = fmaxf(mx, __shfl_xor(mx, 32));
                    if (!__all(mx <= m + THR)) {          // defer-max (T13)
                        float mn = fmaxf(m, mx);
                        float a_ = exp2f(cexp * (m - mn));
                        m = mn;
                        #pragma unroll
                        for (int reg = 0; reg < 16; ++reg) {
                            int src = (reg & 3) + 8 * (reg >> 2) + 4 * hi;
                            float aq = __shfl(a_, src);
                            O0[reg] *= aq;
                            O1[reg] *= aq;
                        }
                        lr *= a_;
                    }
                    float cm = cexp * m;
                    float rs = 0.f;
                    #pragma unroll
                    for (int reg = 0; reg < 16; ++reg) {
                        p[reg] = exp2f(fmaf(cexp, p[reg], -cm));
                        rs += p[reg];
                    }
                    if (navail == 2) {
                        #pragma unroll
                        for (int reg = 16; reg < 32; ++reg) {
                            p[reg] = exp2f(fmaf(cexp, p[reg], -cm));
                            rs += p[reg];
                        }
                    }
                    rs += __shfl_xor(rs, 32);
                    lr += rs;

                    #pragma unroll
                    for (int c = 0; c < 4; ++c) {
                        if (c < navail * 2) {
                            int pb = (c >> 1) * 16 + (c & 1) * 8;
                            int pk01 = cvtpk(p[pb + 0], p[pb + 1]);
                            int pk23 = cvtpk(p[pb + 2], p[pb + 3]);
                            int pk45 = cvtpk(p[pb + 4], p[pb + 5]);
                            int pk67 = cvtpk(p[pb + 6], p[pb + 7]);
                            int sx01 = __shfl_xor(pk01, 32);
                            int sx23 = __shfl_xor(pk23, 32);
                            int sx45 = __shfl_xor(pk45, 32);
                            int sx67 = __shfl_xor(pk67, 32);
                            union { int i[4]; s16x8 v; } u;
                            u.i[0] = hi ? sx45 : pk01;
                            u.i[1] = hi ? sx67 : pk23;
                            u.i[2] = hi ? pk45 : sx01;
                            u.i[3] = hi ? pk67 : sx23;
                            int go = ((c * 2 + hi) ^ xg) * 8;
                            s16x8 vb0 = *(const s16x8*)&Vc[l32 * 64 + go];
                            O0 = mfma32(u.v, vb0, O0);
                            s16x8 vb1 = *(const s16x8*)&Vc[(32 + l32) * 64 + go];
                            O1 = mfma32(u.v, vb1, O1);
                        }
                    }
                }

                hard_barrier();
                if (sc + 2 < c1) STAGE(sc + 2, cur)
                cur ^= 1;
            }
        }

        size_t obase = (size_t)b * S * 1024 + h * 64;
        #pragma unroll
        for (int reg = 0; reg < 16; ++reg) {
            int src = (reg & 3) + 8 * (reg >> 2) + 4 * hi;
            size_t row = obase + (size_t)(qb + src) * 1024;
            pout[row + l32] = f2b(O0[reg]);
            pout[row + 32 + l32] = f2b(O1[reg]);
        }
        if (hi == 0) {
            float2 st; st.x = m; st.y = lr;
            stats[quar * 65536 + ((b * 2048 + qb + l32) * 16 + h)] = st;
        }
    }
#undef STAGE
}

// ------------------------- attention partial merge (x4) ---------------------
__global__ __launch_bounds__(256) void merge_attn(u16* __restrict__ p0,
                                                  const u16* __restrict__ p1,
                                                  const u16* __restrict__ p2,
                                                  const u16* __restrict__ p3,
                                                  const float2* __restrict__ stats) {
    constexpr float cexp = 0.18033688011112042f;
    int gid = blockIdx.x * 256 + threadIdx.x;    // [0, 65536*4)
    int rh = gid >> 2;
    int dc = (gid & 3) * 16;
    int R = rh >> 4, h = rh & 15;
    size_t addr = (size_t)R * 1024 + h * 64 + dc;

    float2 s0 = stats[rh];
    float2 s1 = stats[65536 + rh];
    float2 s2 = stats[131072 + rh];
    float2 s3 = stats[196608 + rh];
    float M = fmaxf(fmaxf(s0.x, s1.x), fmaxf(s2.x, s3.x));
    float a0 = exp2f(cexp * (s0.x - M));
    float a1 = exp2f(cexp * (s1.x - M));
    float a2 = exp2f(cexp * (s2.x - M));
    float a3 = exp2f(cexp * (s3.x - M));
    float inv = 1.f / (a0 * s0.y + a1 * s1.y + a2 * s2.y + a3 * s3.y);
    a0 *= inv; a1 *= inv; a2 *= inv; a3 *= inv;

    u16x4 o[4];
    #pragma unroll
    for (int j = 0; j < 4; ++j) {
        u16x4 q0 = *(const u16x4*)(p0 + addr + j * 4);
        u16x4 q1 = *(const u16x4*)(p1 + addr + j * 4);
        u16x4 q2 = *(const u16x4*)(p2 + addr + j * 4);
        u16x4 q3 = *(const u16x4*)(p3 + addr + j * 4);
        #pragma unroll
        for (int e = 0; e < 4; ++e)
            o[j][e] = f2b(a0 * b2f(q0[e]) + a1 * b2f(q1[e]) +
                          a2 * b2f(q2[e]) + a3 * b2f(q3[e]));
    }
    #pragma unroll
    for (int j = 0; j < 4; ++j)
        *(u16x4*)(p0 + addr + j * 4) = o[j];
}

// --------------------- residual + LayerNorm (row = 1024) --------------------
template<bool WB>
__global__ __launch_bounds__(256) void resln(const float* __restrict__ xa,
                                             const float* __restrict__ xb2,
                                             const float* __restrict__ g,
                                             const float* __restrict__ be,
                                             float* __restrict__ outf,
                                             u16* __restrict__ outb) {
    int row = blockIdx.x;
    int t = threadIdx.x;
    size_t base = (size_t)row * 1024 + t * 4;
    float4 va = *(const float4*)(xa + base);
    float4 vb = *(const float4*)(xb2 + base);
    float v0 = va.x + vb.x, v1 = va.y + vb.y, v2 = va.z + vb.z, v3 = va.w + vb.w;
    float s1 = v0 + v1 + v2 + v3;
    float s2 = v0 * v0 + v1 * v1 + v2 * v2 + v3 * v3;
    #pragma unroll
    for (int off = 32; off >= 1; off >>= 1) {
        s1 += __shfl_down(s1, off);
        s2 += __shfl_down(s2, off);
    }
    __shared__ float r1[4], r2[4];
    if ((t & 63) == 0) { r1[t >> 6] = s1; r2[t >> 6] = s2; }
    __syncthreads();
    s1 = r1[0] + r1[1] + r1[2] + r1[3];
    s2 = r2[0] + r2[1] + r2[2] + r2[3];
    float mean = s1 * (1.f / 1024.f);
    float var = fmaxf((s2 - 1024.f * mean * mean) * (1.f / 1023.f), 0.f);
    float inv = 1.f / (sqrtf(var) + 1e-6f);
    int col = t * 4;
    float y0 = g[col + 0] * ((v0 - mean) * inv) + be[col + 0];
    float y1 = g[col + 1] * ((v1 - mean) * inv) + be[col + 1];
    float y2 = g[col + 2] * ((v2 - mean) * inv) + be[col + 2];
    float y3 = g[col + 3] * ((v3 - mean) * inv) + be[col + 3];
    float4 o = {y0, y1, y2, y3};
    *(float4*)(outf + base) = o;
    if constexpr (WB) {
        u16x4 ob = {f2b(y0), f2b(y1), f2b(y2), f2b(y3)};
        *(u16x4*)(outb + base) = ob;
    }
}

// ---------------------------------------------------------------------------
extern "C" void kernel_launch(void* const* d_in, const int* in_sizes, int n_in,
                              void* d_out, int out_size, void* d_ws, size_t ws_size,
                              hipStream_t stream) {
    (void)in_sizes; (void)n_in; (void)out_size; (void)ws_size;
    const float* x       = (const float*)d_in[0];
    const float* w_attn  = (const float*)d_in[1];
    const float* b_attn  = (const float*)d_in[2];
    const float* w_aproj = (const float*)d_in[3];
    const float* b_aproj = (const float*)d_in[4];
    const float* g1      = (const float*)d_in[5];
    const float* b1      = (const float*)d_in[6];
    const float* w_fc    = (const float*)d_in[7];
    const float* b_fc    = (const float*)d_in[8];
    const float* w_mproj = (const float*)d_in[9];
    const float* b_mproj = (const float*)d_in[10];
    const float* g2      = (const float*)d_in[11];
    const float* b2      = (const float*)d_in[12];
    float* out = (float*)d_out;

    constexpr int M = 4096;           // B*S
    constexpr int D = 1024;

    char* ws = (char*)d_ws;
    u16*   slotA = (u16*)ws;                         // 32 MiB: qkv(24)+vT(8) -> h
    char*  pB    = ws + (32u << 20);                 //  8 MiB: xb -> part0/abuf -> nb
    char*  pC    = ws + (40u << 20);                 //  8 MiB: part1 -> wT
    char*  pD    = ws + (48u << 20);                 // 16 MiB: part2+part3 -> aout -> mout
    char*  pE    = ws + (64u << 20);                 // 16 MiB: stats -> nbuf (fp32)

    u16*   xb    = (u16*)pB;
    u16*   wT    = (u16*)pC;
    u16*   qkv   = slotA;
    u16*   vT    = slotA + (24u << 20) / 2;          // 8 MiB region after qkv
    u16*   part0 = (u16*)pB;                         // becomes merged abuf
    u16*   part1 = (u16*)pC;
    u16*   part2 = (u16*)pD;
    u16*   part3 = (u16*)(pD + (8u << 20));
    float2* stat = (float2*)pE;
    u16*   abuf  = (u16*)pB;
    float* aout  = (float*)pD;
    float* nbuf  = (float*)pE;
    u16*   nb    = (u16*)pB;
    u16*   h     = slotA;
    float* mout  = (float*)pD;

    dim3 blk(256);
    dim3 blk512(512);

    cvt_bf16<<<dim3(4096), blk, 0, stream>>>(x, xb, M * D / 4);

    transpose_bf16<<<dim3(3072 / 32, 1024 / 32), blk, 0, stream>>>(w_attn, wT, 1024, 3072);
    gemm_pl<128, false, u16, true><<<dim3((M / 128) * (3072 / 128)), blk512, 0, stream>>>(
        xb, wT, b_attn, qkv, vT, M, 3072, 1024, 3072);

    attn_kernel<<<dim3(1024), blk, 0, stream>>>(qkv, vT, part0, part1, part2, part3, stat);
    merge_attn<<<dim3(1024), blk, 0, stream>>>(part0, part1, part2, part3, stat);

    transpose_bf16<<<dim3(1024 / 32, 1024 / 32), blk, 0, stream>>>(w_aproj, wT, 1024, 1024);
    gemm_pl3<false, float><<<dim3((M / 128) * (1024 / 64)), blk512, 0, stream>>>(
        abuf, wT, b_aproj, aout, M, 1024, 1024, 1024);

    resln<true><<<dim3(M), blk, 0, stream>>>(x, aout, g1, b1, nbuf, nb);

    transpose_bf16<<<dim3(4096 / 32, 1024 / 32), blk, 0, stream>>>(w_fc, wT, 1024, 4096);
    gemm_pl<128, true, u16, false, true><<<dim3((M / 128) * (4096 / 128)), blk512, 0, stream>>>(
        nb, wT, b_fc, h, nullptr, M, 4096, 1024, 4096);

    transpose_bf16<<<dim3(1024 / 32, 4096 / 32), blk, 0, stream>>>(w_mproj, wT, 4096, 1024);
    gemm_pl3<false, float><<<dim3((M / 128) * (1024 / 64)), blk512, 0, stream>>>(
        h, wT, b_mproj, mout, M, 1024, 4096, 1024);

    resln<false><<<dim3(M), blk, 0, stream>>>(nbuf, mout, g2, b2, out, nullptr);
}

// Round 22
// 259.094 us; speedup vs baseline: 1.0344x; 1.0259x over previous
//
#include <hip/hip_runtime.h>
#include <type_traits>

// ---------------------------------------------------------------------------
// GPT block forward: B=2, S=2048, D=1024, H=16, DH=64
// Round 22: qkv GEMM -> C2D 2-D XCD chunk (was the last kernel on the old
// M-fastest mapping; r17 profile showed 135MB FETCH = 13x over-fetch).
// Everything else byte-identical to round 19/21 best (265.5 us).
// ---------------------------------------------------------------------------

typedef unsigned short u16;
typedef short s16x8 __attribute__((ext_vector_type(8)));
typedef unsigned short u16x4 __attribute__((ext_vector_type(4)));
typedef float f32x4 __attribute__((ext_vector_type(4)));
typedef float f32x16 __attribute__((ext_vector_type(16)));

__device__ __forceinline__ u16 f2b(float f) {
    union { float f; unsigned u; } x{f};
    unsigned r = x.u + 0x7FFFu + ((x.u >> 16) & 1u);  // RNE
    return (u16)(r >> 16);
}

__device__ __forceinline__ float b2f(u16 v) {
    union { unsigned u; float f; } x;
    x.u = ((unsigned)v) << 16;
    return x.f;
}

__device__ __forceinline__ f32x4 mfma16(s16x8 a, s16x8 b, f32x4 c) {
    return __builtin_amdgcn_mfma_f32_16x16x32_bf16(a, b, c, 0, 0, 0);
}

__device__ __forceinline__ f32x16 mfma32(s16x8 a, s16x8 b, f32x16 c) {
    return __builtin_amdgcn_mfma_f32_32x32x16_bf16(a, b, c, 0, 0, 0);
}

__device__ __forceinline__ int cvtpk(float a, float b) {
    int r;
    asm("v_cvt_pk_bf16_f32 %0, %1, %2" : "=v"(r) : "v"(a), "v"(b));
    return r;
}

__device__ __forceinline__ void gld_lds16(const u16* g, const u16* l) {
    __builtin_amdgcn_global_load_lds(
        (const __attribute__((address_space(1))) void*)g,
        (__attribute__((address_space(3))) void*)l, 16, 0, 0);
}

__device__ __forceinline__ void hard_barrier() {
    __builtin_amdgcn_sched_barrier(0);
    __builtin_amdgcn_s_barrier();
    __builtin_amdgcn_sched_barrier(0);
}

// --------------------------- fp32 -> bf16 convert ---------------------------
__global__ __launch_bounds__(256) void cvt_bf16(const float* __restrict__ in,
                                                u16* __restrict__ out, int n4) {
    int i = blockIdx.x * 256 + threadIdx.x;
    if (i < n4) {
        float4 v = ((const float4*)in)[i];
        u16x4 o = {f2b(v.x), f2b(v.y), f2b(v.z), f2b(v.w)};
        ((u16x4*)out)[i] = o;
    }
}

// ------------------- transpose fp32 [K,N] -> bf16 [N,K] ---------------------
__global__ __launch_bounds__(256) void transpose_bf16(const float* __restrict__ W,
                                                      u16* __restrict__ WT,
                                                      int K, int N) {
    __shared__ float t[32][33];
    int tx = threadIdx.x & 31, ty = threadIdx.x >> 5;
    int n0 = blockIdx.x * 32, k0 = blockIdx.y * 32;
    #pragma unroll
    for (int r = ty; r < 32; r += 8)
        t[r][tx] = W[(size_t)(k0 + r) * N + n0 + tx];
    __syncthreads();
    #pragma unroll
    for (int r = ty; r < 32; r += 8)
        WT[(size_t)(n0 + r) * K + k0 + tx] = f2b(t[tx][r]);
}

// -------- MFMA GEMM, 2-buffer counted-vmcnt, 8 waves on 128xBN tile ---------
// VW: qkv V-third blocks also write transposed vT. C2D: 2-D XCD chunk
// (needs nbm==32, ntn even; bijective for qkv ntn=24 and fc ntn=32).
template<int BN, bool GELU, typename OT, bool VW = false, bool C2D = false>
__global__ __launch_bounds__(512) void gemm_pl(const u16* __restrict__ A,
                                               const u16* __restrict__ BT,
                                               const float* __restrict__ bias,
                                               OT* __restrict__ C,
                                               u16* __restrict__ vTout,
                                               int M, int N, int K, int ldc) {
    constexpr int NF = BN / 64;
    constexpr int BNI = BN / 64;
    constexpr int LTOT = 2 + BNI;
    __shared__ u16 As[2][128 * 64];
    __shared__ u16 Bs[2][BN * 64];

    int t = threadIdx.x;
    int w = t >> 6, l = t & 63, l16 = l & 15, lh = l >> 4;
    int wr = w >> 2, wc = w & 3;

    int nbm = M >> 7;
    int id = blockIdx.x;
    size_t m0, n0;
    if constexpr (C2D) {
        int x = id & 7, j = id >> 3;
        int ntn2 = (int)(gridDim.x >> 6);
        int mi = (x & 3) * 8 + (j & 7);
        int ni = (x >> 2) * ntn2 + (j >> 3);
        m0 = (size_t)mi * 128;
        n0 = (size_t)ni * BN;
    } else {
        int cpx = gridDim.x >> 3;
        int id2 = (id & 7) * cpx + (id >> 3);
        m0 = (size_t)(id2 % nbm) * 128;
        n0 = (size_t)(id2 / nbm) * BN;
    }

    int rowA = t >> 3;
    int gc2 = (t & 7) ^ (rowA & 7);
    const u16* Ag = A + (m0 + rowA) * (size_t)K + gc2 * 8;
    const u16* Bg = BT + (n0 + rowA) * (size_t)K + gc2 * 8;
    int wb = w * 512;

    f32x4 acc[4][NF] = {};
    int rx = (l16 & 7) * 8;

    #pragma unroll
    for (int j = 0; j < 2; ++j)
        gld_lds16(Ag + (size_t)j * 64 * K, &As[0][j * 4096 + wb]);
    #pragma unroll
    for (int j = 0; j < BNI; ++j)
        gld_lds16(Bg + (size_t)j * 64 * K, &Bs[0][j * 4096 + wb]);
    #pragma unroll
    for (int j = 0; j < 2; ++j)
        gld_lds16(Ag + 64 + (size_t)j * 64 * K, &As[1][j * 4096 + wb]);
    #pragma unroll
    for (int j = 0; j < BNI; ++j)
        gld_lds16(Bg + 64 + (size_t)j * 64 * K, &Bs[1][j * 4096 + wb]);

#define GTILE(CB, kk, LAST)                                                   \
    {                                                                         \
        if (LAST) asm volatile("s_waitcnt vmcnt(0)" ::: "memory");            \
        else      asm volatile("s_waitcnt vmcnt(%0)" :: "n"(LTOT) : "memory");\
        hard_barrier();                                                       \
        __builtin_amdgcn_s_setprio(1);                                        \
        _Pragma("unroll")                                                     \
        for (int ks = 0; ks < 2; ++ks) {                                      \
            s16x8 af[4], bf[NF];                                              \
            _Pragma("unroll")                                                 \
            for (int fm = 0; fm < 4; ++fm) {                                  \
                int row = wr * 64 + fm * 16 + l16;                            \
                int col = ((ks * 4 + lh) * 8) ^ rx;                           \
                af[fm] = *(const s16x8*)&As[CB][row * 64 + col];              \
            }                                                                 \
            _Pragma("unroll")                                                 \
            for (int fn = 0; fn < NF; ++fn) {                                 \
                int row = wc * (BN / 4) + fn * 16 + l16;                      \
                int col = ((ks * 4 + lh) * 8) ^ rx;                           \
                bf[fn] = *(const s16x8*)&Bs[CB][row * 64 + col];              \
            }                                                                 \
            _Pragma("unroll")                                                 \
            for (int fm = 0; fm < 4; ++fm)                                    \
                _Pragma("unroll")                                             \
                for (int fn = 0; fn < NF; ++fn)                               \
                    acc[fm][fn] = mfma16(af[fm], bf[fn], acc[fm][fn]);        \
        }                                                                     \
        __builtin_amdgcn_s_setprio(0);                                        \
        hard_barrier();                                                       \
        if ((kk) + 128 < K) {                                                 \
            const u16* Ap = Ag + (kk) + 128;                                  \
            _Pragma("unroll")                                                 \
            for (int j = 0; j < 2; ++j)                                       \
                gld_lds16(Ap + (size_t)j * 64 * K, &As[CB][j * 4096 + wb]);   \
            const u16* Bp = Bg + (kk) + 128;                                  \
            _Pragma("unroll")                                                 \
            for (int j = 0; j < BNI; ++j)                                     \
                gld_lds16(Bp + (size_t)j * 64 * K, &Bs[CB][j * 4096 + wb]);   \
        }                                                                     \
    }

    for (int k0 = 0; k0 < K; k0 += 128) {
        GTILE(0, k0, (k0 + 64 >= K))
        GTILE(1, k0 + 64, (k0 + 128 >= K))
    }
#undef GTILE

    #pragma unroll
    for (int fn = 0; fn < NF; ++fn) {
        size_t col = n0 + wc * (BN / 4) + fn * 16 + l16;
        float bs = bias[col];
        #pragma unroll
        for (int fm = 0; fm < 4; ++fm) {
            size_t row0 = m0 + wr * 64 + fm * 16 + lh * 4;
            u16x4 pack;
            #pragma unroll
            for (int i = 0; i < 4; ++i) {
                float v = acc[fm][fn][i] + bs;
                if constexpr (GELU) {
                    float x3 = v * v * v;
                    v = 0.5f * v * (1.f + tanhf(0.7978845608f * (v + 0.044715f * x3)));
                }
                if constexpr (std::is_same<OT, u16>::value) {
                    u16 q = f2b(v);
                    C[(row0 + i) * ldc + col] = q;
                    pack[i] = q;
                } else {
                    C[(row0 + i) * ldc + col] = v;
                }
            }
            if constexpr (VW) {
                if (n0 >= 2048) {      // V third (block-uniform)
                    int hh = ((int)col - 2048) >> 6;
                    int dd = ((int)col - 2048) & 63;
                    size_t vrow = (size_t)(((row0 >> 11) * 16 + hh) * 64 + dd);
                    *(u16x4*)(vTout + vrow * 2048 + (row0 & 2047)) = pack;
                }
            }
        }
    }
}

// ---- MFMA GEMM, 3-buffer 2-deep counted-vmcnt, BN=64 (aproj/mproj) ---------
template<bool GELU, typename OT>
__global__ __launch_bounds__(512) void gemm_pl3(const u16* __restrict__ A,
                                                const u16* __restrict__ BT,
                                                const float* __restrict__ bias,
                                                OT* __restrict__ C,
                                                int M, int N, int K, int ldc) {
    __shared__ u16 As[3][128 * 64];
    __shared__ u16 Bs[3][64 * 64];

    int t = threadIdx.x;
    int w = t >> 6, l = t & 63, l16 = l & 15, lh = l >> 4;
    int wr = w >> 2, wc = w & 3;

    int id = blockIdx.x;
    int x = id & 7, j = id >> 3;                 // j in 0..63
    int mi = (x & 3) * 8 + (j & 7);              // 0..31
    int ni = (x >> 2) * 8 + (j >> 3);            // 0..15
    size_t m0 = (size_t)mi * 128;
    size_t n0 = (size_t)ni * 64;

    int rowA = t >> 3;
    int gc2 = (t & 7) ^ (rowA & 7);
    const u16* Ag = A + (m0 + rowA) * (size_t)K + gc2 * 8;
    const u16* Bg = BT + (n0 + rowA) * (size_t)K + gc2 * 8;
    int wb = w * 512;

    f32x4 acc[4] = {};
    int rx = (l16 & 7) * 8;

#define STAGE3(KK, BUF)                                                       \
    {                                                                         \
        gld_lds16(Ag + (KK), &As[BUF][wb]);                                   \
        gld_lds16(Ag + (KK) + (size_t)64 * K, &As[BUF][4096 + wb]);           \
        gld_lds16(Bg + (KK), &Bs[BUF][wb]);                                   \
    }

    int NT = K >> 6;
    STAGE3(0, 0)
    STAGE3(64, 1)
    if (NT > 2) STAGE3(128, 2)

    int cur = 0;
    #pragma unroll 1
    for (int kt = 0; kt < NT; ++kt) {
        if (kt + 2 < NT)      asm volatile("s_waitcnt vmcnt(6)" ::: "memory");
        else if (kt + 1 < NT) asm volatile("s_waitcnt vmcnt(3)" ::: "memory");
        else                  asm volatile("s_waitcnt vmcnt(0)" ::: "memory");
        hard_barrier();

        __builtin_amdgcn_s_setprio(1);
        #pragma unroll
        for (int ks = 0; ks < 2; ++ks) {
            s16x8 af[4], bf;
            #pragma unroll
            for (int fm = 0; fm < 4; ++fm) {
                int row = wr * 64 + fm * 16 + l16;
                int col = ((ks * 4 + lh) * 8) ^ rx;
                af[fm] = *(const s16x8*)&As[cur][row * 64 + col];
            }
            {
                int row = wc * 16 + l16;
                int col = ((ks * 4 + lh) * 8) ^ rx;
                bf = *(const s16x8*)&Bs[cur][row * 64 + col];
            }
            #pragma unroll
            for (int fm = 0; fm < 4; ++fm)
                acc[fm] = mfma16(af[fm], bf, acc[fm]);
        }
        __builtin_amdgcn_s_setprio(0);
        hard_barrier();

        if (kt + 3 < NT) STAGE3((size_t)(kt + 3) * 64, cur)
        cur = (cur == 2) ? 0 : cur + 1;
    }
#undef STAGE3

    size_t col = n0 + wc * 16 + l16;
    float bs = bias[col];
    #pragma unroll
    for (int fm = 0; fm < 4; ++fm) {
        size_t row0 = m0 + wr * 64 + fm * 16 + lh * 4;
        #pragma unroll
        for (int i = 0; i < 4; ++i) {
            float v = acc[fm][i] + bs;
            if constexpr (GELU) {
                float x3 = v * v * v;
                v = 0.5f * v * (1.f + tanhf(0.7978845608f * (v + 0.044715f * x3)));
            }
            if constexpr (std::is_same<OT, u16>::value)
                C[(row0 + i) * ldc + col] = f2b(v);
            else
                C[(row0 + i) * ldc + col] = v;
        }
    }
}

// --------------------------- causal attention -------------------------------
__global__ __launch_bounds__(256) void attn_kernel(const u16* __restrict__ qkv,
                                                   const u16* __restrict__ vT,
                                                   u16* __restrict__ p0,
                                                   u16* __restrict__ p1,
                                                   u16* __restrict__ p2,
                                                   u16* __restrict__ p3,
                                                   float2* __restrict__ stats) {
    constexpr int S = 2048, D3 = 3072, Dm = 1024;
    __shared__ u16 Kl[2][64 * 64];
    __shared__ u16 Vt[2][64 * 64];

    int t = threadIdx.x;
    int w = t >> 6, l = t & 63;
    int l32 = l & 31, hi = l >> 5;
    int bid = blockIdx.x;
    int bh = (bid & 7) * 4 + ((bid >> 3) & 3);
    int rest = bid >> 5;                 // 0..31
    int quar = rest & 3;
    int pr = rest >> 2;                  // 0..7
    int b = bh >> 4, h = bh & 15;
    size_t base = (size_t)b * S * D3;

    u16* pout = quar == 0 ? p0 : (quar == 1 ? p1 : (quar == 2 ? p2 : p3));

    int rK0 = t >> 3, gK = t & 7;
    int rK1 = rK0 + 32;
    size_t koff0 = (size_t)rK0 * D3 + (size_t)((gK ^ (rK0 & 7)) * 8);
    size_t koff1 = (size_t)rK1 * D3 + (size_t)((gK ^ (rK1 & 7)) * 8);
    const u16* kbase = qkv + base + Dm + h * 64;
    size_t voff0 = (size_t)(bh * 64 + rK0) * 2048 + (size_t)((gK ^ (rK0 & 7)) * 8);
    size_t voff1 = (size_t)(bh * 64 + 32 + rK0) * 2048 + (size_t)((gK ^ (rK0 & 7)) * 8);

    constexpr float cexp = 0.18033688011112042f;   // 0.125 * log2(e)
    constexpr float THR = 64.0f;                    // defer-max threshold
    int xg = l32 & 7;

#define STAGE(SC, BUF)                                                        \
    {                                                                         \
        size_t ko_ = (size_t)(SC) * 64 * D3;                                  \
        int kvb_ = (SC) * 64;                                                 \
        gld_lds16(kbase + ko_ + koff0, &Kl[BUF][w * 512]);                    \
        gld_lds16(kbase + ko_ + koff1, &Kl[BUF][2048 + w * 512]);             \
        gld_lds16(vT + voff0 + kvb_, &Vt[BUF][w * 512]);                      \
        gld_lds16(vT + voff1 + kvb_, &Vt[BUF][2048 + w * 512]);               \
    }

    #pragma unroll 1
    for (int ph = 0; ph < 2; ++ph) {
        int qt = ph ? (15 - pr) : pr;
        int qb = qt * 128 + w * 32;
        int nst = 2 * (qt + 1);
        int c0 = (nst * quar) >> 2;
        int c1 = (nst * (quar + 1)) >> 2;

        f32x16 O0 = {}, O1 = {};
        float m = -1e30f, lr = 0.f;

        if (c0 < c1) {
            s16x8 qf[4];
            const u16* qp = qkv + base + (size_t)(qb + l32) * D3 + h * 64 + hi * 8;
            #pragma unroll
            for (int kk = 0; kk < 4; ++kk)
                qf[kk] = *(const s16x8*)(qp + kk * 16);

            STAGE(c0, 0)
            if (c0 + 1 < c1) STAGE(c0 + 1, 1)

            int cur = 0;
            #pragma unroll 1
            for (int sc = c0; sc < c1; ++sc) {
                if (sc + 1 < c1)
                    asm volatile("s_waitcnt vmcnt(4)" ::: "memory");
                else
                    asm volatile("s_waitcnt vmcnt(0)" ::: "memory");
                hard_barrier();

                int kvb = sc * 64;
                int navail = ((qb - kvb) >> 5) + 1;
                if (navail > 0) {
                    if (navail > 2) navail = 2;
                    const u16* Kc = Kl[cur];
                    const u16* Vc = Vt[cur];
                    f32x16 sa0 = {}, sa1 = {};
                    #pragma unroll
                    for (int kk = 0; kk < 4; ++kk) {
                        s16x8 kf = *(const s16x8*)&Kc[l32 * 64 + (((2 * kk + hi) ^ xg) * 8)];
                        sa0 = mfma32(kf, qf[kk], sa0);
                    }
                    if (navail == 2) {
                        #pragma unroll
                        for (int kk = 0; kk < 4; ++kk) {
                            s16x8 kf = *(const s16x8*)&Kc[(32 + l32) * 64 + (((2 * kk + hi) ^ xg) * 8)];
                            sa1 = mfma32(kf, qf[kk], sa1);
                        }
                    }
                    bool diag0 = (kvb == qb);
                    bool diag1 = (kvb + 32 == qb);
                    float p[32];
                    float mx = -1e30f;
                    if (diag0 | diag1) {             // wave-uniform branch
                        #pragma unroll
                        for (int reg = 0; reg < 16; ++reg) {
                            int kvloc = (reg & 3) + 8 * (reg >> 2) + 4 * hi;
                            float s0 = sa0[reg];
                            if (diag0 && kvloc > l32) s0 = -1e30f;
                            p[reg] = s0;
                            mx = fmaxf(mx, s0);
                        }
                        if (navail == 2) {
                            #pragma unroll
                            for (int reg = 0; reg < 16; ++reg) {
                                int kvloc = (reg & 3) + 8 * (reg >> 2) + 4 * hi;
                                float s1 = sa1[reg];
                                if (diag1 && kvloc > l32) s1 = -1e30f;
                                p[16 + reg] = s1;
                                mx = fmaxf(mx, s1);
                            }
                        }
                    } else {
                        #pragma unroll
                        for (int reg = 0; reg < 16; ++reg) {
                            p[reg] = sa0[reg];
                            mx = fmaxf(mx, sa0[reg]);
                        }
                        if (navail == 2) {
                            #pragma unroll
                            for (int reg = 0; reg < 16; ++reg) {
                                p[16 + reg] = sa1[reg];
                                mx = fmaxf(mx, sa1[reg]);
                            }
                        }
                    }
                    mx = fmaxf(mx, __shfl_xor(mx, 32));
                    if (!__all(mx <= m + THR)) {          // defer-max (T13)
                        float mn = fmaxf(m, mx);
                        float a_ = exp2f(cexp * (m - mn));
                        m = mn;
                        #pragma unroll
                        for (int reg = 0; reg < 16; ++reg) {
                            int src = (reg & 3) + 8 * (reg >> 2) + 4 * hi;
                            float aq = __shfl(a_, src);
                            O0[reg] *= aq;
                            O1[reg] *= aq;
                        }
                        lr *= a_;
                    }
                    float cm = cexp * m;
                    float rs = 0.f;
                    #pragma unroll
                    for (int reg = 0; reg < 16; ++reg) {
                        p[reg] = exp2f(fmaf(cexp, p[reg], -cm));
                        rs += p[reg];
                    }
                    if (navail == 2) {
                        #pragma unroll
                        for (int reg = 16; reg < 32; ++reg) {
                            p[reg] = exp2f(fmaf(cexp, p[reg], -cm));
                            rs += p[reg];
                        }
                    }
                    rs += __shfl_xor(rs, 32);
                    lr += rs;

                    #pragma unroll
                    for (int c = 0; c < 4; ++c) {
                        if (c < navail * 2) {
                            int pb = (c >> 1) * 16 + (c & 1) * 8;
                            int pk01 = cvtpk(p[pb + 0], p[pb + 1]);
                            int pk23 = cvtpk(p[pb + 2], p[pb + 3]);
                            int pk45 = cvtpk(p[pb + 4], p[pb + 5]);
                            int pk67 = cvtpk(p[pb + 6], p[pb + 7]);
                            int sx01 = __shfl_xor(pk01, 32);
                            int sx23 = __shfl_xor(pk23, 32);
                            int sx45 = __shfl_xor(pk45, 32);
                            int sx67 = __shfl_xor(pk67, 32);
                            union { int i[4]; s16x8 v; } u;
                            u.i[0] = hi ? sx45 : pk01;
                            u.i[1] = hi ? sx67 : pk23;
                            u.i[2] = hi ? pk45 : sx01;
                            u.i[3] = hi ? pk67 : sx23;
                            int go = ((c * 2 + hi) ^ xg) * 8;
                            s16x8 vb0 = *(const s16x8*)&Vc[l32 * 64 + go];
                            O0 = mfma32(u.v, vb0, O0);
                            s16x8 vb1 = *(const s16x8*)&Vc[(32 + l32) * 64 + go];
                            O1 = mfma32(u.v, vb1, O1);
                        }
                    }
                }

                hard_barrier();
                if (sc + 2 < c1) STAGE(sc + 2, cur)
                cur ^= 1;
            }
        }

        size_t obase = (size_t)b * S * 1024 + h * 64;
        #pragma unroll
        for (int reg = 0; reg < 16; ++reg) {
            int src = (reg & 3) + 8 * (reg >> 2) + 4 * hi;
            size_t row = obase + (size_t)(qb + src) * 1024;
            pout[row + l32] = f2b(O0[reg]);
            pout[row + 32 + l32] = f2b(O1[reg]);
        }
        if (hi == 0) {
            float2 st; st.x = m; st.y = lr;
            stats[quar * 65536 + ((b * 2048 + qb + l32) * 16 + h)] = st;
        }
    }
#undef STAGE
}

// ------------------------- attention partial merge (x4) ---------------------
__global__ __launch_bounds__(256) void merge_attn(u16* __restrict__ p0,
                                                  const u16* __restrict__ p1,
                                                  const u16* __restrict__ p2,
                                                  const u16* __restrict__ p3,
                                                  const float2* __restrict__ stats) {
    constexpr float cexp = 0.18033688011112042f;
    int gid = blockIdx.x * 256 + threadIdx.x;    // [0, 65536*4)
    int rh = gid >> 2;
    int dc = (gid & 3) * 16;
    int R = rh >> 4, h = rh & 15;
    size_t addr = (size_t)R * 1024 + h * 64 + dc;

    float2 s0 = stats[rh];
    float2 s1 = stats[65536 + rh];
    float2 s2 = stats[131072 + rh];
    float2 s3 = stats[196608 + rh];
    float M = fmaxf(fmaxf(s0.x, s1.x), fmaxf(s2.x, s3.x));
    float a0 = exp2f(cexp * (s0.x - M));
    float a1 = exp2f(cexp * (s1.x - M));
    float a2 = exp2f(cexp * (s2.x - M));
    float a3 = exp2f(cexp * (s3.x - M));
    float inv = 1.f / (a0 * s0.y + a1 * s1.y + a2 * s2.y + a3 * s3.y);
    a0 *= inv; a1 *= inv; a2 *= inv; a3 *= inv;

    u16x4 o[4];
    #pragma unroll
    for (int j = 0; j < 4; ++j) {
        u16x4 q0 = *(const u16x4*)(p0 + addr + j * 4);
        u16x4 q1 = *(const u16x4*)(p1 + addr + j * 4);
        u16x4 q2 = *(const u16x4*)(p2 + addr + j * 4);
        u16x4 q3 = *(const u16x4*)(p3 + addr + j * 4);
        #pragma unroll
        for (int e = 0; e < 4; ++e)
            o[j][e] = f2b(a0 * b2f(q0[e]) + a1 * b2f(q1[e]) +
                          a2 * b2f(q2[e]) + a3 * b2f(q3[e]));
    }
    #pragma unroll
    for (int j = 0; j < 4; ++j)
        *(u16x4*)(p0 + addr + j * 4) = o[j];
}

// --------------------- residual + LayerNorm (row = 1024) --------------------
template<bool WB>
__global__ __launch_bounds__(256) void resln(const float* __restrict__ xa,
                                             const float* __restrict__ xb2,
                                             const float* __restrict__ g,
                                             const float* __restrict__ be,
                                             float* __restrict__ outf,
                                             u16* __restrict__ outb) {
    int row = blockIdx.x;
    int t = threadIdx.x;
    size_t base = (size_t)row * 1024 + t * 4;
    float4 va = *(const float4*)(xa + base);
    float4 vb = *(const float4*)(xb2 + base);
    float v0 = va.x + vb.x, v1 = va.y + vb.y, v2 = va.z + vb.z, v3 = va.w + vb.w;
    float s1 = v0 + v1 + v2 + v3;
    float s2 = v0 * v0 + v1 * v1 + v2 * v2 + v3 * v3;
    #pragma unroll
    for (int off = 32; off >= 1; off >>= 1) {
        s1 += __shfl_down(s1, off);
        s2 += __shfl_down(s2, off);
    }
    __shared__ float r1[4], r2[4];
    if ((t & 63) == 0) { r1[t >> 6] = s1; r2[t >> 6] = s2; }
    __syncthreads();
    s1 = r1[0] + r1[1] + r1[2] + r1[3];
    s2 = r2[0] + r2[1] + r2[2] + r2[3];
    float mean = s1 * (1.f / 1024.f);
    float var = fmaxf((s2 - 1024.f * mean * mean) * (1.f / 1023.f), 0.f);
    float inv = 1.f / (sqrtf(var) + 1e-6f);
    int col = t * 4;
    float y0 = g[col + 0] * ((v0 - mean) * inv) + be[col + 0];
    float y1 = g[col + 1] * ((v1 - mean) * inv) + be[col + 1];
    float y2 = g[col + 2] * ((v2 - mean) * inv) + be[col + 2];
    float y3 = g[col + 3] * ((v3 - mean) * inv) + be[col + 3];
    float4 o = {y0, y1, y2, y3};
    *(float4*)(outf + base) = o;
    if constexpr (WB) {
        u16x4 ob = {f2b(y0), f2b(y1), f2b(y2), f2b(y3)};
        *(u16x4*)(outb + base) = ob;
    }
}

// ---------------------------------------------------------------------------
extern "C" void kernel_launch(void* const* d_in, const int* in_sizes, int n_in,
                              void* d_out, int out_size, void* d_ws, size_t ws_size,
                              hipStream_t stream) {
    (void)in_sizes; (void)n_in; (void)out_size; (void)ws_size;
    const float* x       = (const float*)d_in[0];
    const float* w_attn  = (const float*)d_in[1];
    const float* b_attn  = (const float*)d_in[2];
    const float* w_aproj = (const float*)d_in[3];
    const float* b_aproj = (const float*)d_in[4];
    const float* g1      = (const float*)d_in[5];
    const float* b1      = (const float*)d_in[6];
    const float* w_fc    = (const float*)d_in[7];
    const float* b_fc    = (const float*)d_in[8];
    const float* w_mproj = (const float*)d_in[9];
    const float* b_mproj = (const float*)d_in[10];
    const float* g2      = (const float*)d_in[11];
    const float* b2      = (const float*)d_in[12];
    float* out = (float*)d_out;

    constexpr int M = 4096;           // B*S
    constexpr int D = 1024;

    char* ws = (char*)d_ws;
    u16*   slotA = (u16*)ws;                         // 32 MiB: qkv(24)+vT(8) -> h
    char*  pB    = ws + (32u << 20);                 //  8 MiB: xb -> part0/abuf -> nb
    char*  pC    = ws + (40u << 20);                 //  8 MiB: part1 -> wT
    char*  pD    = ws + (48u << 20);                 // 16 MiB: part2+part3 -> aout -> mout
    char*  pE    = ws + (64u << 20);                 // 16 MiB: stats -> nbuf (fp32)

    u16*   xb    = (u16*)pB;
    u16*   wT    = (u16*)pC;
    u16*   qkv   = slotA;
    u16*   vT    = slotA + (24u << 20) / 2;          // 8 MiB region after qkv
    u16*   part0 = (u16*)pB;                         // becomes merged abuf
    u16*   part1 = (u16*)pC;
    u16*   part2 = (u16*)pD;
    u16*   part3 = (u16*)(pD + (8u << 20));
    float2* stat = (float2*)pE;
    u16*   abuf  = (u16*)pB;
    float* aout  = (float*)pD;
    float* nbuf  = (float*)pE;
    u16*   nb    = (u16*)pB;
    u16*   h     = slotA;
    float* mout  = (float*)pD;

    dim3 blk(256);
    dim3 blk512(512);

    cvt_bf16<<<dim3(4096), blk, 0, stream>>>(x, xb, M * D / 4);

    transpose_bf16<<<dim3(3072 / 32, 1024 / 32), blk, 0, stream>>>(w_attn, wT, 1024, 3072);
    gemm_pl<128, false, u16, true, true><<<dim3((M / 128) * (3072 / 128)), blk512, 0, stream>>>(
        xb, wT, b_attn, qkv, vT, M, 3072, 1024, 3072);

    attn_kernel<<<dim3(1024), blk, 0, stream>>>(qkv, vT, part0, part1, part2, part3, stat);
    merge_attn<<<dim3(1024), blk, 0, stream>>>(part0, part1, part2, part3, stat);

    transpose_bf16<<<dim3(1024 / 32, 1024 / 32), blk, 0, stream>>>(w_aproj, wT, 1024, 1024);
    gemm_pl3<false, float><<<dim3((M / 128) * (1024 / 64)), blk512, 0, stream>>>(
        abuf, wT, b_aproj, aout, M, 1024, 1024, 1024);

    resln<true><<<dim3(M), blk, 0, stream>>>(x, aout, g1, b1, nbuf, nb);

    transpose_bf16<<<dim3(4096 / 32, 1024 / 32), blk, 0, stream>>>(w_fc, wT, 1024, 4096);
    gemm_pl<128, true, u16, false, true><<<dim3((M / 128) * (4096 / 128)), blk512, 0, stream>>>(
        nb, wT, b_fc, h, nullptr, M, 4096, 1024, 4096);

    transpose_bf16<<<dim3(1024 / 32, 4096 / 32), blk, 0, stream>>>(w_mproj, wT, 4096, 1024);
    gemm_pl3<false, float><<<dim3((M / 128) * (1024 / 64)), blk512, 0, stream>>>(
        h, wT, b_mproj, mout, M, 1024, 4096, 1024);

    resln<false><<<dim3(M), blk, 0, stream>>>(nbuf, mout, g2, b2, out, nullptr);
}

// Round 24
// 258.494 us; speedup vs baseline: 1.0368x; 1.0023x over previous
//
#include <hip/hip_runtime.h>
#include <type_traits>

// ---------------------------------------------------------------------------
// GPT block forward: B=2, S=2048, D=1024, H=16, DH=64
// Round 24: revert to round-22 verified best (259.1 us). The 1-barrier
// 3-buffer attention raced (marginal absmax 0.117); stage-after-compute
// 2-barrier pattern restored. All-C2D GEMMs, fused vT, kv-split x4.
// ---------------------------------------------------------------------------

typedef unsigned short u16;
typedef short s16x8 __attribute__((ext_vector_type(8)));
typedef unsigned short u16x4 __attribute__((ext_vector_type(4)));
typedef float f32x4 __attribute__((ext_vector_type(4)));
typedef float f32x16 __attribute__((ext_vector_type(16)));

__device__ __forceinline__ u16 f2b(float f) {
    union { float f; unsigned u; } x{f};
    unsigned r = x.u + 0x7FFFu + ((x.u >> 16) & 1u);  // RNE
    return (u16)(r >> 16);
}

__device__ __forceinline__ float b2f(u16 v) {
    union { unsigned u; float f; } x;
    x.u = ((unsigned)v) << 16;
    return x.f;
}

__device__ __forceinline__ f32x4 mfma16(s16x8 a, s16x8 b, f32x4 c) {
    return __builtin_amdgcn_mfma_f32_16x16x32_bf16(a, b, c, 0, 0, 0);
}

__device__ __forceinline__ f32x16 mfma32(s16x8 a, s16x8 b, f32x16 c) {
    return __builtin_amdgcn_mfma_f32_32x32x16_bf16(a, b, c, 0, 0, 0);
}

__device__ __forceinline__ int cvtpk(float a, float b) {
    int r;
    asm("v_cvt_pk_bf16_f32 %0, %1, %2" : "=v"(r) : "v"(a), "v"(b));
    return r;
}

__device__ __forceinline__ void gld_lds16(const u16* g, const u16* l) {
    __builtin_amdgcn_global_load_lds(
        (const __attribute__((address_space(1))) void*)g,
        (__attribute__((address_space(3))) void*)l, 16, 0, 0);
}

__device__ __forceinline__ void hard_barrier() {
    __builtin_amdgcn_sched_barrier(0);
    __builtin_amdgcn_s_barrier();
    __builtin_amdgcn_sched_barrier(0);
}

// --------------------------- fp32 -> bf16 convert ---------------------------
__global__ __launch_bounds__(256) void cvt_bf16(const float* __restrict__ in,
                                                u16* __restrict__ out, int n4) {
    int i = blockIdx.x * 256 + threadIdx.x;
    if (i < n4) {
        float4 v = ((const float4*)in)[i];
        u16x4 o = {f2b(v.x), f2b(v.y), f2b(v.z), f2b(v.w)};
        ((u16x4*)out)[i] = o;
    }
}

// ------------------- transpose fp32 [K,N] -> bf16 [N,K] ---------------------
__global__ __launch_bounds__(256) void transpose_bf16(const float* __restrict__ W,
                                                      u16* __restrict__ WT,
                                                      int K, int N) {
    __shared__ float t[32][33];
    int tx = threadIdx.x & 31, ty = threadIdx.x >> 5;
    int n0 = blockIdx.x * 32, k0 = blockIdx.y * 32;
    #pragma unroll
    for (int r = ty; r < 32; r += 8)
        t[r][tx] = W[(size_t)(k0 + r) * N + n0 + tx];
    __syncthreads();
    #pragma unroll
    for (int r = ty; r < 32; r += 8)
        WT[(size_t)(n0 + r) * K + k0 + tx] = f2b(t[tx][r]);
}

// -------- MFMA GEMM, 2-buffer counted-vmcnt, 8 waves on 128xBN tile ---------
// VW: qkv V-third blocks also write transposed vT. C2D: 2-D XCD chunk.
template<int BN, bool GELU, typename OT, bool VW = false, bool C2D = false>
__global__ __launch_bounds__(512) void gemm_pl(const u16* __restrict__ A,
                                               const u16* __restrict__ BT,
                                               const float* __restrict__ bias,
                                               OT* __restrict__ C,
                                               u16* __restrict__ vTout,
                                               int M, int N, int K, int ldc) {
    constexpr int NF = BN / 64;
    constexpr int BNI = BN / 64;
    constexpr int LTOT = 2 + BNI;
    __shared__ u16 As[2][128 * 64];
    __shared__ u16 Bs[2][BN * 64];

    int t = threadIdx.x;
    int w = t >> 6, l = t & 63, l16 = l & 15, lh = l >> 4;
    int wr = w >> 2, wc = w & 3;

    int nbm = M >> 7;
    int id = blockIdx.x;
    size_t m0, n0;
    if constexpr (C2D) {
        int x = id & 7, j = id >> 3;
        int ntn2 = (int)(gridDim.x >> 6);
        int mi = (x & 3) * 8 + (j & 7);
        int ni = (x >> 2) * ntn2 + (j >> 3);
        m0 = (size_t)mi * 128;
        n0 = (size_t)ni * BN;
    } else {
        int cpx = gridDim.x >> 3;
        int id2 = (id & 7) * cpx + (id >> 3);
        m0 = (size_t)(id2 % nbm) * 128;
        n0 = (size_t)(id2 / nbm) * BN;
    }

    int rowA = t >> 3;
    int gc2 = (t & 7) ^ (rowA & 7);
    const u16* Ag = A + (m0 + rowA) * (size_t)K + gc2 * 8;
    const u16* Bg = BT + (n0 + rowA) * (size_t)K + gc2 * 8;
    int wb = w * 512;

    f32x4 acc[4][NF] = {};
    int rx = (l16 & 7) * 8;

    #pragma unroll
    for (int j = 0; j < 2; ++j)
        gld_lds16(Ag + (size_t)j * 64 * K, &As[0][j * 4096 + wb]);
    #pragma unroll
    for (int j = 0; j < BNI; ++j)
        gld_lds16(Bg + (size_t)j * 64 * K, &Bs[0][j * 4096 + wb]);
    #pragma unroll
    for (int j = 0; j < 2; ++j)
        gld_lds16(Ag + 64 + (size_t)j * 64 * K, &As[1][j * 4096 + wb]);
    #pragma unroll
    for (int j = 0; j < BNI; ++j)
        gld_lds16(Bg + 64 + (size_t)j * 64 * K, &Bs[1][j * 4096 + wb]);

#define GTILE(CB, kk, LAST)                                                   \
    {                                                                         \
        if (LAST) asm volatile("s_waitcnt vmcnt(0)" ::: "memory");            \
        else      asm volatile("s_waitcnt vmcnt(%0)" :: "n"(LTOT) : "memory");\
        hard_barrier();                                                       \
        __builtin_amdgcn_s_setprio(1);                                        \
        _Pragma("unroll")                                                     \
        for (int ks = 0; ks < 2; ++ks) {                                      \
            s16x8 af[4], bf[NF];                                              \
            _Pragma("unroll")                                                 \
            for (int fm = 0; fm < 4; ++fm) {                                  \
                int row = wr * 64 + fm * 16 + l16;                            \
                int col = ((ks * 4 + lh) * 8) ^ rx;                           \
                af[fm] = *(const s16x8*)&As[CB][row * 64 + col];              \
            }                                                                 \
            _Pragma("unroll")                                                 \
            for (int fn = 0; fn < NF; ++fn) {                                 \
                int row = wc * (BN / 4) + fn * 16 + l16;                      \
                int col = ((ks * 4 + lh) * 8) ^ rx;                           \
                bf[fn] = *(const s16x8*)&Bs[CB][row * 64 + col];              \
            }                                                                 \
            _Pragma("unroll")                                                 \
            for (int fm = 0; fm < 4; ++fm)                                    \
                _Pragma("unroll")                                             \
                for (int fn = 0; fn < NF; ++fn)                               \
                    acc[fm][fn] = mfma16(af[fm], bf[fn], acc[fm][fn]);        \
        }                                                                     \
        __builtin_amdgcn_s_setprio(0);                                        \
        hard_barrier();                                                       \
        if ((kk) + 128 < K) {                                                 \
            const u16* Ap = Ag + (kk) + 128;                                  \
            _Pragma("unroll")                                                 \
            for (int j = 0; j < 2; ++j)                                       \
                gld_lds16(Ap + (size_t)j * 64 * K, &As[CB][j * 4096 + wb]);   \
            const u16* Bp = Bg + (kk) + 128;                                  \
            _Pragma("unroll")                                                 \
            for (int j = 0; j < BNI; ++j)                                     \
                gld_lds16(Bp + (size_t)j * 64 * K, &Bs[CB][j * 4096 + wb]);   \
        }                                                                     \
    }

    for (int k0 = 0; k0 < K; k0 += 128) {
        GTILE(0, k0, (k0 + 64 >= K))
        GTILE(1, k0 + 64, (k0 + 128 >= K))
    }
#undef GTILE

    #pragma unroll
    for (int fn = 0; fn < NF; ++fn) {
        size_t col = n0 + wc * (BN / 4) + fn * 16 + l16;
        float bs = bias[col];
        #pragma unroll
        for (int fm = 0; fm < 4; ++fm) {
            size_t row0 = m0 + wr * 64 + fm * 16 + lh * 4;
            u16x4 pack;
            #pragma unroll
            for (int i = 0; i < 4; ++i) {
                float v = acc[fm][fn][i] + bs;
                if constexpr (GELU) {
                    float x3 = v * v * v;
                    v = 0.5f * v * (1.f + tanhf(0.7978845608f * (v + 0.044715f * x3)));
                }
                if constexpr (std::is_same<OT, u16>::value) {
                    u16 q = f2b(v);
                    C[(row0 + i) * ldc + col] = q;
                    pack[i] = q;
                } else {
                    C[(row0 + i) * ldc + col] = v;
                }
            }
            if constexpr (VW) {
                if (n0 >= 2048) {      // V third (block-uniform)
                    int hh = ((int)col - 2048) >> 6;
                    int dd = ((int)col - 2048) & 63;
                    size_t vrow = (size_t)(((row0 >> 11) * 16 + hh) * 64 + dd);
                    *(u16x4*)(vTout + vrow * 2048 + (row0 & 2047)) = pack;
                }
            }
        }
    }
}

// ---- MFMA GEMM, 3-buffer 2-deep counted-vmcnt, BN=64 (aproj/mproj) ---------
template<bool GELU, typename OT>
__global__ __launch_bounds__(512) void gemm_pl3(const u16* __restrict__ A,
                                                const u16* __restrict__ BT,
                                                const float* __restrict__ bias,
                                                OT* __restrict__ C,
                                                int M, int N, int K, int ldc) {
    __shared__ u16 As[3][128 * 64];
    __shared__ u16 Bs[3][64 * 64];

    int t = threadIdx.x;
    int w = t >> 6, l = t & 63, l16 = l & 15, lh = l >> 4;
    int wr = w >> 2, wc = w & 3;

    int id = blockIdx.x;
    int x = id & 7, j = id >> 3;                 // j in 0..63
    int mi = (x & 3) * 8 + (j & 7);              // 0..31
    int ni = (x >> 2) * 8 + (j >> 3);            // 0..15
    size_t m0 = (size_t)mi * 128;
    size_t n0 = (size_t)ni * 64;

    int rowA = t >> 3;
    int gc2 = (t & 7) ^ (rowA & 7);
    const u16* Ag = A + (m0 + rowA) * (size_t)K + gc2 * 8;
    const u16* Bg = BT + (n0 + rowA) * (size_t)K + gc2 * 8;
    int wb = w * 512;

    f32x4 acc[4] = {};
    int rx = (l16 & 7) * 8;

#define STAGE3(KK, BUF)                                                       \
    {                                                                         \
        gld_lds16(Ag + (KK), &As[BUF][wb]);                                   \
        gld_lds16(Ag + (KK) + (size_t)64 * K, &As[BUF][4096 + wb]);           \
        gld_lds16(Bg + (KK), &Bs[BUF][wb]);                                   \
    }

    int NT = K >> 6;
    STAGE3(0, 0)
    STAGE3(64, 1)
    if (NT > 2) STAGE3(128, 2)

    int cur = 0;
    #pragma unroll 1
    for (int kt = 0; kt < NT; ++kt) {
        if (kt + 2 < NT)      asm volatile("s_waitcnt vmcnt(6)" ::: "memory");
        else if (kt + 1 < NT) asm volatile("s_waitcnt vmcnt(3)" ::: "memory");
        else                  asm volatile("s_waitcnt vmcnt(0)" ::: "memory");
        hard_barrier();

        __builtin_amdgcn_s_setprio(1);
        #pragma unroll
        for (int ks = 0; ks < 2; ++ks) {
            s16x8 af[4], bf;
            #pragma unroll
            for (int fm = 0; fm < 4; ++fm) {
                int row = wr * 64 + fm * 16 + l16;
                int col = ((ks * 4 + lh) * 8) ^ rx;
                af[fm] = *(const s16x8*)&As[cur][row * 64 + col];
            }
            {
                int row = wc * 16 + l16;
                int col = ((ks * 4 + lh) * 8) ^ rx;
                bf = *(const s16x8*)&Bs[cur][row * 64 + col];
            }
            #pragma unroll
            for (int fm = 0; fm < 4; ++fm)
                acc[fm] = mfma16(af[fm], bf, acc[fm]);
        }
        __builtin_amdgcn_s_setprio(0);
        hard_barrier();

        if (kt + 3 < NT) STAGE3((size_t)(kt + 3) * 64, cur)
        cur = (cur == 2) ? 0 : cur + 1;
    }
#undef STAGE3

    size_t col = n0 + wc * 16 + l16;
    float bs = bias[col];
    #pragma unroll
    for (int fm = 0; fm < 4; ++fm) {
        size_t row0 = m0 + wr * 64 + fm * 16 + lh * 4;
        #pragma unroll
        for (int i = 0; i < 4; ++i) {
            float v = acc[fm][i] + bs;
            if constexpr (GELU) {
                float x3 = v * v * v;
                v = 0.5f * v * (1.f + tanhf(0.7978845608f * (v + 0.044715f * x3)));
            }
            if constexpr (std::is_same<OT, u16>::value)
                C[(row0 + i) * ldc + col] = f2b(v);
            else
                C[(row0 + i) * ldc + col] = v;
        }
    }
}

// --------------------------- causal attention -------------------------------
__global__ __launch_bounds__(256) void attn_kernel(const u16* __restrict__ qkv,
                                                   const u16* __restrict__ vT,
                                                   u16* __restrict__ p0,
                                                   u16* __restrict__ p1,
                                                   u16* __restrict__ p2,
                                                   u16* __restrict__ p3,
                                                   float2* __restrict__ stats) {
    constexpr int S = 2048, D3 = 3072, Dm = 1024;
    __shared__ u16 Kl[2][64 * 64];
    __shared__ u16 Vt[2][64 * 64];

    int t = threadIdx.x;
    int w = t >> 6, l = t & 63;
    int l32 = l & 31, hi = l >> 5;
    int bid = blockIdx.x;
    int bh = (bid & 7) * 4 + ((bid >> 3) & 3);
    int rest = bid >> 5;                 // 0..31
    int quar = rest & 3;
    int pr = rest >> 2;                  // 0..7
    int b = bh >> 4, h = bh & 15;
    size_t base = (size_t)b * S * D3;

    u16* pout = quar == 0 ? p0 : (quar == 1 ? p1 : (quar == 2 ? p2 : p3));

    int rK0 = t >> 3, gK = t & 7;
    int rK1 = rK0 + 32;
    size_t koff0 = (size_t)rK0 * D3 + (size_t)((gK ^ (rK0 & 7)) * 8);
    size_t koff1 = (size_t)rK1 * D3 + (size_t)((gK ^ (rK1 & 7)) * 8);
    const u16* kbase = qkv + base + Dm + h * 64;
    size_t voff0 = (size_t)(bh * 64 + rK0) * 2048 + (size_t)((gK ^ (rK0 & 7)) * 8);
    size_t voff1 = (size_t)(bh * 64 + 32 + rK0) * 2048 + (size_t)((gK ^ (rK0 & 7)) * 8);

    constexpr float cexp = 0.18033688011112042f;   // 0.125 * log2(e)
    constexpr float THR = 64.0f;                    // defer-max threshold
    int xg = l32 & 7;

#define STAGE(SC, BUF)                                                        \
    {                                                                         \
        size_t ko_ = (size_t)(SC) * 64 * D3;                                  \
        int kvb_ = (SC) * 64;                                                 \
        gld_lds16(kbase + ko_ + koff0, &Kl[BUF][w * 512]);                    \
        gld_lds16(kbase + ko_ + koff1, &Kl[BUF][2048 + w * 512]);             \
        gld_lds16(vT + voff0 + kvb_, &Vt[BUF][w * 512]);                      \
        gld_lds16(vT + voff1 + kvb_, &Vt[BUF][2048 + w * 512]);               \
    }

    #pragma unroll 1
    for (int ph = 0; ph < 2; ++ph) {
        int qt = ph ? (15 - pr) : pr;
        int qb = qt * 128 + w * 32;
        int nst = 2 * (qt + 1);
        int c0 = (nst * quar) >> 2;
        int c1 = (nst * (quar + 1)) >> 2;

        f32x16 O0 = {}, O1 = {};
        float m = -1e30f, lr = 0.f;

        if (c0 < c1) {
            s16x8 qf[4];
            const u16* qp = qkv + base + (size_t)(qb + l32) * D3 + h * 64 + hi * 8;
            #pragma unroll
            for (int kk = 0; kk < 4; ++kk)
                qf[kk] = *(const s16x8*)(qp + kk * 16);

            STAGE(c0, 0)
            if (c0 + 1 < c1) STAGE(c0 + 1, 1)

            int cur = 0;
            #pragma unroll 1
            for (int sc = c0; sc < c1; ++sc) {
                if (sc + 1 < c1)
                    asm volatile("s_waitcnt vmcnt(4)" ::: "memory");
                else
                    asm volatile("s_waitcnt vmcnt(0)" ::: "memory");
                hard_barrier();

                int kvb = sc * 64;
                int navail = ((qb - kvb) >> 5) + 1;
                if (navail > 0) {
                    if (navail > 2) navail = 2;
                    const u16* Kc = Kl[cur];
                    const u16* Vc = Vt[cur];
                    f32x16 sa0 = {}, sa1 = {};
                    #pragma unroll
                    for (int kk = 0; kk < 4; ++kk) {
                        s16x8 kf = *(const s16x8*)&Kc[l32 * 64 + (((2 * kk + hi) ^ xg) * 8)];
                        sa0 = mfma32(kf, qf[kk], sa0);
                    }
                    if (navail == 2) {
                        #pragma unroll
                        for (int kk = 0; kk < 4; ++kk) {
                            s16x8 kf = *(const s16x8*)&Kc[(32 + l32) * 64 + (((2 * kk + hi) ^ xg) * 8)];
                            sa1 = mfma32(kf, qf[kk], sa1);
                        }
                    }
                    bool diag0 = (kvb == qb);
                    bool diag1 = (kvb + 32 == qb);
                    float p[32];
                    float mx = -1e30f;
                    if (diag0 | diag1) {             // wave-uniform branch
                        #pragma unroll
                        for (int reg = 0; reg < 16; ++reg) {
                            int kvloc = (reg & 3) + 8 * (reg >> 2) + 4 * hi;
                            float s0 = sa0[reg];
                            if (diag0 && kvloc > l32) s0 = -1e30f;
                            p[reg] = s0;
                            mx = fmaxf(mx, s0);
                        }
                        if (navail == 2) {
                            #pragma unroll
                            for (int reg = 0; reg < 16; ++reg) {
                                int kvloc = (reg & 3) + 8 * (reg >> 2) + 4 * hi;
                                float s1 = sa1[reg];
                                if (diag1 && kvloc > l32) s1 = -1e30f;
                                p[16 + reg] = s1;
                                mx = fmaxf(mx, s1);
                            }
                        }
                    } else {
                        #pragma unroll
                        for (int reg = 0; reg < 16; ++reg) {
                            p[reg] = sa0[reg];
                            mx = fmaxf(mx, sa0[reg]);
                        }
                        if (navail == 2) {
                            #pragma unroll
                            for (int reg = 0; reg < 16; ++reg) {
                                p[16 + reg] = sa1[reg];
                                mx = fmaxf(mx, sa1[reg]);
                            }
                        }
                    }
                    mx = fmaxf(mx, __shfl_xor(mx, 32));
                    if (!__all(mx <= m + THR)) {          // defer-max (T13)
                        float mn = fmaxf(m, mx);
                        float a_ = exp2f(cexp * (m - mn));
                        m = mn;
                        #pragma unroll
                        for (int reg = 0; reg < 16; ++reg) {
                            int src = (reg & 3) + 8 * (reg >> 2) + 4 * hi;
                            float aq = __shfl(a_, src);
                            O0[reg] *= aq;
                            O1[reg] *= aq;
                        }
                        lr *= a_;
                    }
                    float cm = cexp * m;
                    float rs = 0.f;
                    #pragma unroll
                    for (int reg = 0; reg < 16; ++reg) {
                        p[reg] = exp2f(fmaf(cexp, p[reg], -cm));
                        rs += p[reg];
                    }
                    if (navail == 2) {
                        #pragma unroll
                        for (int reg = 16; reg < 32; ++reg) {
                            p[reg] = exp2f(fmaf(cexp, p[reg], -cm));
                            rs += p[reg];
                        }
                    }
                    rs += __shfl_xor(rs, 32);
                    lr += rs;

                    #pragma unroll
                    for (int c = 0; c < 4; ++c) {
                        if (c < navail * 2) {
                            int pb = (c >> 1) * 16 + (c & 1) * 8;
                            int pk01 = cvtpk(p[pb + 0], p[pb + 1]);
                            int pk23 = cvtpk(p[pb + 2], p[pb + 3]);
                            int pk45 = cvtpk(p[pb + 4], p[pb + 5]);
                            int pk67 = cvtpk(p[pb + 6], p[pb + 7]);
                            int sx01 = __shfl_xor(pk01, 32);
                            int sx23 = __shfl_xor(pk23, 32);
                            int sx45 = __shfl_xor(pk45, 32);
                            int sx67 = __shfl_xor(pk67, 32);
                            union { int i[4]; s16x8 v; } u;
                            u.i[0] = hi ? sx45 : pk01;
                            u.i[1] = hi ? sx67 : pk23;
                            u.i[2] = hi ? pk45 : sx01;
                            u.i[3] = hi ? pk67 : sx23;
                            int go = ((c * 2 + hi) ^ xg) * 8;
                            s16x8 vb0 = *(const s16x8*)&Vc[l32 * 64 + go];
                            O0 = mfma32(u.v, vb0, O0);
                            s16x8 vb1 = *(const s16x8*)&Vc[(32 + l32) * 64 + go];
                            O1 = mfma32(u.v, vb1, O1);
                        }
                    }
                }

                hard_barrier();
                if (sc + 2 < c1) STAGE(sc + 2, cur)
                cur ^= 1;
            }
        }

        size_t obase = (size_t)b * S * 1024 + h * 64;
        #pragma unroll
        for (int reg = 0; reg < 16; ++reg) {
            int src = (reg & 3) + 8 * (reg >> 2) + 4 * hi;
            size_t row = obase + (size_t)(qb + src) * 1024;
            pout[row + l32] = f2b(O0[reg]);
            pout[row + 32 + l32] = f2b(O1[reg]);
        }
        if (hi == 0) {
            float2 st; st.x = m; st.y = lr;
            stats[quar * 65536 + ((b * 2048 + qb + l32) * 16 + h)] = st;
        }
    }
#undef STAGE
}

// ------------------------- attention partial merge (x4) ---------------------
__global__ __launch_bounds__(256) void merge_attn(u16* __restrict__ p0,
                                                  const u16* __restrict__ p1,
                                                  const u16* __restrict__ p2,
                                                  const u16* __restrict__ p3,
                                                  const float2* __restrict__ stats) {
    constexpr float cexp = 0.18033688011112042f;
    int gid = blockIdx.x * 256 + threadIdx.x;    // [0, 65536*4)
    int rh = gid >> 2;
    int dc = (gid & 3) * 16;
    int R = rh >> 4, h = rh & 15;
    size_t addr = (size_t)R * 1024 + h * 64 + dc;

    float2 s0 = stats[rh];
    float2 s1 = stats[65536 + rh];
    float2 s2 = stats[131072 + rh];
    float2 s3 = stats[196608 + rh];
    float M = fmaxf(fmaxf(s0.x, s1.x), fmaxf(s2.x, s3.x));
    float a0 = exp2f(cexp * (s0.x - M));
    float a1 = exp2f(cexp * (s1.x - M));
    float a2 = exp2f(cexp * (s2.x - M));
    float a3 = exp2f(cexp * (s3.x - M));
    float inv = 1.f / (a0 * s0.y + a1 * s1.y + a2 * s2.y + a3 * s3.y);
    a0 *= inv; a1 *= inv; a2 *= inv; a3 *= inv;

    u16x4 o[4];
    #pragma unroll
    for (int j = 0; j < 4; ++j) {
        u16x4 q0 = *(const u16x4*)(p0 + addr + j * 4);
        u16x4 q1 = *(const u16x4*)(p1 + addr + j * 4);
        u16x4 q2 = *(const u16x4*)(p2 + addr + j * 4);
        u16x4 q3 = *(const u16x4*)(p3 + addr + j * 4);
        #pragma unroll
        for (int e = 0; e < 4; ++e)
            o[j][e] = f2b(a0 * b2f(q0[e]) + a1 * b2f(q1[e]) +
                          a2 * b2f(q2[e]) + a3 * b2f(q3[e]));
    }
    #pragma unroll
    for (int j = 0; j < 4; ++j)
        *(u16x4*)(p0 + addr + j * 4) = o[j];
}

// --------------------- residual + LayerNorm (row = 1024) --------------------
template<bool WB>
__global__ __launch_bounds__(256) void resln(const float* __restrict__ xa,
                                             const float* __restrict__ xb2,
                                             const float* __restrict__ g,
                                             const float* __restrict__ be,
                                             float* __restrict__ outf,
                                             u16* __restrict__ outb) {
    int row = blockIdx.x;
    int t = threadIdx.x;
    size_t base = (size_t)row * 1024 + t * 4;
    float4 va = *(const float4*)(xa + base);
    float4 vb = *(const float4*)(xb2 + base);
    float v0 = va.x + vb.x, v1 = va.y + vb.y, v2 = va.z + vb.z, v3 = va.w + vb.w;
    float s1 = v0 + v1 + v2 + v3;
    float s2 = v0 * v0 + v1 * v1 + v2 * v2 + v3 * v3;
    #pragma unroll
    for (int off = 32; off >= 1; off >>= 1) {
        s1 += __shfl_down(s1, off);
        s2 += __shfl_down(s2, off);
    }
    __shared__ float r1[4], r2[4];
    if ((t & 63) == 0) { r1[t >> 6] = s1; r2[t >> 6] = s2; }
    __syncthreads();
    s1 = r1[0] + r1[1] + r1[2] + r1[3];
    s2 = r2[0] + r2[1] + r2[2] + r2[3];
    float mean = s1 * (1.f / 1024.f);
    float var = fmaxf((s2 - 1024.f * mean * mean) * (1.f / 1023.f), 0.f);
    float inv = 1.f / (sqrtf(var) + 1e-6f);
    int col = t * 4;
    float y0 = g[col + 0] * ((v0 - mean) * inv) + be[col + 0];
    float y1 = g[col + 1] * ((v1 - mean) * inv) + be[col + 1];
    float y2 = g[col + 2] * ((v2 - mean) * inv) + be[col + 2];
    float y3 = g[col + 3] * ((v3 - mean) * inv) + be[col + 3];
    float4 o = {y0, y1, y2, y3};
    *(float4*)(outf + base) = o;
    if constexpr (WB) {
        u16x4 ob = {f2b(y0), f2b(y1), f2b(y2), f2b(y3)};
        *(u16x4*)(outb + base) = ob;
    }
}

// ---------------------------------------------------------------------------
extern "C" void kernel_launch(void* const* d_in, const int* in_sizes, int n_in,
                              void* d_out, int out_size, void* d_ws, size_t ws_size,
                              hipStream_t stream) {
    (void)in_sizes; (void)n_in; (void)out_size; (void)ws_size;
    const float* x       = (const float*)d_in[0];
    const float* w_attn  = (const float*)d_in[1];
    const float* b_attn  = (const float*)d_in[2];
    const float* w_aproj = (const float*)d_in[3];
    const float* b_aproj = (const float*)d_in[4];
    const float* g1      = (const float*)d_in[5];
    const float* b1      = (const float*)d_in[6];
    const float* w_fc    = (const float*)d_in[7];
    const float* b_fc    = (const float*)d_in[8];
    const float* w_mproj = (const float*)d_in[9];
    const float* b_mproj = (const float*)d_in[10];
    const float* g2      = (const float*)d_in[11];
    const float* b2      = (const float*)d_in[12];
    float* out = (float*)d_out;

    constexpr int M = 4096;           // B*S
    constexpr int D = 1024;

    char* ws = (char*)d_ws;
    u16*   slotA = (u16*)ws;                         // 32 MiB: qkv(24)+vT(8) -> h
    char*  pB    = ws + (32u << 20);                 //  8 MiB: xb -> part0/abuf -> nb
    char*  pC    = ws + (40u << 20);                 //  8 MiB: part1 -> wT
    char*  pD    = ws + (48u << 20);                 // 16 MiB: part2+part3 -> aout -> mout
    char*  pE    = ws + (64u << 20);                 // 16 MiB: stats -> nbuf (fp32)

    u16*   xb    = (u16*)pB;
    u16*   wT    = (u16*)pC;
    u16*   qkv   = slotA;
    u16*   vT    = slotA + (24u << 20) / 2;          // 8 MiB region after qkv
    u16*   part0 = (u16*)pB;                         // becomes merged abuf
    u16*   part1 = (u16*)pC;
    u16*   part2 = (u16*)pD;
    u16*   part3 = (u16*)(pD + (8u << 20));
    float2* stat = (float2*)pE;
    u16*   abuf  = (u16*)pB;
    float* aout  = (float*)pD;
    float* nbuf  = (float*)pE;
    u16*   nb    = (u16*)pB;
    u16*   h     = slotA;
    float* mout  = (float*)pD;

    dim3 blk(256);
    dim3 blk512(512);

    cvt_bf16<<<dim3(4096), blk, 0, stream>>>(x, xb, M * D / 4);

    transpose_bf16<<<dim3(3072 / 32, 1024 / 32), blk, 0, stream>>>(w_attn, wT, 1024, 3072);
    gemm_pl<128, false, u16, true, true><<<dim3((M / 128) * (3072 / 128)), blk512, 0, stream>>>(
        xb, wT, b_attn, qkv, vT, M, 3072, 1024, 3072);

    attn_kernel<<<dim3(1024), blk, 0, stream>>>(qkv, vT, part0, part1, part2, part3, stat);
    merge_attn<<<dim3(1024), blk, 0, stream>>>(part0, part1, part2, part3, stat);

    transpose_bf16<<<dim3(1024 / 32, 1024 / 32), blk, 0, stream>>>(w_aproj, wT, 1024, 1024);
    gemm_pl3<false, float><<<dim3((M / 128) * (1024 / 64)), blk512, 0, stream>>>(
        abuf, wT, b_aproj, aout, M, 1024, 1024, 1024);

    resln<true><<<dim3(M), blk, 0, stream>>>(x, aout, g1, b1, nbuf, nb);

    transpose_bf16<<<dim3(4096 / 32, 1024 / 32), blk, 0, stream>>>(w_fc, wT, 1024, 4096);
    gemm_pl<128, true, u16, false, true><<<dim3((M / 128) * (4096 / 128)), blk512, 0, stream>>>(
        nb, wT, b_fc, h, nullptr, M, 4096, 1024, 4096);

    transpose_bf16<<<dim3(1024 / 32, 4096 / 32), blk, 0, stream>>>(w_mproj, wT, 4096, 1024);
    gemm_pl3<false, float><<<dim3((M / 128) * (1024 / 64)), blk512, 0, stream>>>(
        h, wT, b_mproj, mout, M, 1024, 4096, 1024);

    resln<false><<<dim3(M), blk, 0, stream>>>(nbuf, mout, g2, b2, out, nullptr);
}

// Round 25
// 252.575 us; speedup vs baseline: 1.0610x; 1.0234x over previous
//
#include <hip/hip_runtime.h>
#include <type_traits>

// ---------------------------------------------------------------------------
// GPT block forward: B=2, S=2048, D=1024, H=16, DH=64
// Round 25: fuse independent small kernels (block-role branch, zero sync
// changes): {cvt + w_attn transpose}, {merge + w_aproj transpose -> pE+8M},
// {resln1 + w_fc transpose}. GEMMs/attention byte-identical to r24 (258.5us).
// ---------------------------------------------------------------------------

typedef unsigned short u16;
typedef short s16x8 __attribute__((ext_vector_type(8)));
typedef unsigned short u16x4 __attribute__((ext_vector_type(4)));
typedef float f32x4 __attribute__((ext_vector_type(4)));
typedef float f32x16 __attribute__((ext_vector_type(16)));

__device__ __forceinline__ u16 f2b(float f) {
    union { float f; unsigned u; } x{f};
    unsigned r = x.u + 0x7FFFu + ((x.u >> 16) & 1u);  // RNE
    return (u16)(r >> 16);
}

__device__ __forceinline__ float b2f(u16 v) {
    union { unsigned u; float f; } x;
    x.u = ((unsigned)v) << 16;
    return x.f;
}

__device__ __forceinline__ f32x4 mfma16(s16x8 a, s16x8 b, f32x4 c) {
    return __builtin_amdgcn_mfma_f32_16x16x32_bf16(a, b, c, 0, 0, 0);
}

__device__ __forceinline__ f32x16 mfma32(s16x8 a, s16x8 b, f32x16 c) {
    return __builtin_amdgcn_mfma_f32_32x32x16_bf16(a, b, c, 0, 0, 0);
}

__device__ __forceinline__ int cvtpk(float a, float b) {
    int r;
    asm("v_cvt_pk_bf16_f32 %0, %1, %2" : "=v"(r) : "v"(a), "v"(b));
    return r;
}

__device__ __forceinline__ void gld_lds16(const u16* g, const u16* l) {
    __builtin_amdgcn_global_load_lds(
        (const __attribute__((address_space(1))) void*)g,
        (__attribute__((address_space(3))) void*)l, 16, 0, 0);
}

__device__ __forceinline__ void hard_barrier() {
    __builtin_amdgcn_sched_barrier(0);
    __builtin_amdgcn_s_barrier();
    __builtin_amdgcn_sched_barrier(0);
}

// ------------------------- device-side primitives ---------------------------
__device__ __forceinline__ void d_cvt(const float* __restrict__ in,
                                      u16* __restrict__ out, int i) {
    float4 v = ((const float4*)in)[i];
    u16x4 o = {f2b(v.x), f2b(v.y), f2b(v.z), f2b(v.w)};
    ((u16x4*)out)[i] = o;
}

__device__ __forceinline__ void d_tr(const float* __restrict__ W,
                                     u16* __restrict__ WT, int K, int N,
                                     int bx, int by, int t, float (*tile)[33]) {
    int tx = t & 31, ty = t >> 5;
    int n0 = bx * 32, k0 = by * 32;
    #pragma unroll
    for (int r = ty; r < 32; r += 8)
        tile[r][tx] = W[(size_t)(k0 + r) * N + n0 + tx];
    __syncthreads();
    #pragma unroll
    for (int r = ty; r < 32; r += 8)
        WT[(size_t)(n0 + r) * K + k0 + tx] = f2b(tile[tx][r]);
}

__device__ __forceinline__ void d_merge(u16* __restrict__ p0,
                                        const u16* __restrict__ p1,
                                        const u16* __restrict__ p2,
                                        const u16* __restrict__ p3,
                                        const float2* __restrict__ stats,
                                        int gid) {
    constexpr float cexp = 0.18033688011112042f;
    int rh = gid >> 2;
    int dc = (gid & 3) * 16;
    int R = rh >> 4, h = rh & 15;
    size_t addr = (size_t)R * 1024 + h * 64 + dc;

    float2 s0 = stats[rh];
    float2 s1 = stats[65536 + rh];
    float2 s2 = stats[131072 + rh];
    float2 s3 = stats[196608 + rh];
    float M = fmaxf(fmaxf(s0.x, s1.x), fmaxf(s2.x, s3.x));
    float a0 = exp2f(cexp * (s0.x - M));
    float a1 = exp2f(cexp * (s1.x - M));
    float a2 = exp2f(cexp * (s2.x - M));
    float a3 = exp2f(cexp * (s3.x - M));
    float inv = 1.f / (a0 * s0.y + a1 * s1.y + a2 * s2.y + a3 * s3.y);
    a0 *= inv; a1 *= inv; a2 *= inv; a3 *= inv;

    u16x4 o[4];
    #pragma unroll
    for (int j = 0; j < 4; ++j) {
        u16x4 q0 = *(const u16x4*)(p0 + addr + j * 4);
        u16x4 q1 = *(const u16x4*)(p1 + addr + j * 4);
        u16x4 q2 = *(const u16x4*)(p2 + addr + j * 4);
        u16x4 q3 = *(const u16x4*)(p3 + addr + j * 4);
        #pragma unroll
        for (int e = 0; e < 4; ++e)
            o[j][e] = f2b(a0 * b2f(q0[e]) + a1 * b2f(q1[e]) +
                          a2 * b2f(q2[e]) + a3 * b2f(q3[e]));
    }
    #pragma unroll
    for (int j = 0; j < 4; ++j)
        *(u16x4*)(p0 + addr + j * 4) = o[j];
}

template<bool WB>
__device__ __forceinline__ void d_resln(const float* __restrict__ xa,
                                        const float* __restrict__ xb2,
                                        const float* __restrict__ g,
                                        const float* __restrict__ be,
                                        float* __restrict__ outf,
                                        u16* __restrict__ outb,
                                        int row, int t,
                                        float* r1, float* r2) {
    size_t base = (size_t)row * 1024 + t * 4;
    float4 va = *(const float4*)(xa + base);
    float4 vb = *(const float4*)(xb2 + base);
    float v0 = va.x + vb.x, v1 = va.y + vb.y, v2 = va.z + vb.z, v3 = va.w + vb.w;
    float s1 = v0 + v1 + v2 + v3;
    float s2 = v0 * v0 + v1 * v1 + v2 * v2 + v3 * v3;
    #pragma unroll
    for (int off = 32; off >= 1; off >>= 1) {
        s1 += __shfl_down(s1, off);
        s2 += __shfl_down(s2, off);
    }
    if ((t & 63) == 0) { r1[t >> 6] = s1; r2[t >> 6] = s2; }
    __syncthreads();
    s1 = r1[0] + r1[1] + r1[2] + r1[3];
    s2 = r2[0] + r2[1] + r2[2] + r2[3];
    float mean = s1 * (1.f / 1024.f);
    float var = fmaxf((s2 - 1024.f * mean * mean) * (1.f / 1023.f), 0.f);
    float inv = 1.f / (sqrtf(var) + 1e-6f);
    int col = t * 4;
    float y0 = g[col + 0] * ((v0 - mean) * inv) + be[col + 0];
    float y1 = g[col + 1] * ((v1 - mean) * inv) + be[col + 1];
    float y2 = g[col + 2] * ((v2 - mean) * inv) + be[col + 2];
    float y3 = g[col + 3] * ((v3 - mean) * inv) + be[col + 3];
    float4 o = {y0, y1, y2, y3};
    *(float4*)(outf + base) = o;
    if constexpr (WB) {
        u16x4 ob = {f2b(y0), f2b(y1), f2b(y2), f2b(y3)};
        *(u16x4*)(outb + base) = ob;
    }
}

// --------------------------- fused small kernels ----------------------------
// pre: blocks [0,4096) cvt x->xb ; [4096,7168) transpose w_attn -> wT
__global__ __launch_bounds__(256) void fused_pre(const float* __restrict__ x,
                                                 u16* __restrict__ xb,
                                                 const float* __restrict__ w_attn,
                                                 u16* __restrict__ wT) {
    __shared__ float tile[32][33];
    int bid = blockIdx.x, t = threadIdx.x;
    if (bid < 4096) {
        d_cvt(x, xb, bid * 256 + t);
    } else {
        int j = bid - 4096;
        d_tr(w_attn, wT, 1024, 3072, j % 96, j / 96, t, tile);
    }
}

// mid: blocks [0,1024) merge partials ; [1024,2048) transpose w_aproj -> wTa
__global__ __launch_bounds__(256) void fused_mid(u16* __restrict__ p0,
                                                 const u16* __restrict__ p1,
                                                 const u16* __restrict__ p2,
                                                 const u16* __restrict__ p3,
                                                 const float2* __restrict__ stats,
                                                 const float* __restrict__ w_aproj,
                                                 u16* __restrict__ wTa) {
    __shared__ float tile[32][33];
    int bid = blockIdx.x, t = threadIdx.x;
    if (bid < 1024) {
        d_merge(p0, p1, p2, p3, stats, bid * 256 + t);
    } else {
        int j = bid - 1024;
        d_tr(w_aproj, wTa, 1024, 1024, j % 32, j / 32, t, tile);
    }
}

// ln1: blocks [0,4096) resln<true> ; [4096,8192) transpose w_fc -> wTf
__global__ __launch_bounds__(256) void fused_ln1(const float* __restrict__ x,
                                                 const float* __restrict__ aout,
                                                 const float* __restrict__ g1,
                                                 const float* __restrict__ b1,
                                                 float* __restrict__ nbuf,
                                                 u16* __restrict__ nb,
                                                 const float* __restrict__ w_fc,
                                                 u16* __restrict__ wTf) {
    __shared__ float tile[32][33];
    __shared__ float r1[4], r2[4];
    int bid = blockIdx.x, t = threadIdx.x;
    if (bid < 4096) {
        d_resln<true>(x, aout, g1, b1, nbuf, nb, bid, t, r1, r2);
    } else {
        int j = bid - 4096;
        d_tr(w_fc, wTf, 1024, 4096, j % 128, j / 128, t, tile);
    }
}

// ------------------- transpose fp32 [K,N] -> bf16 [N,K] ---------------------
__global__ __launch_bounds__(256) void transpose_bf16(const float* __restrict__ W,
                                                      u16* __restrict__ WT,
                                                      int K, int N) {
    __shared__ float t[32][33];
    d_tr(W, WT, K, N, blockIdx.x, blockIdx.y, threadIdx.x, t);
}

// -------- MFMA GEMM, 2-buffer counted-vmcnt, 8 waves on 128xBN tile ---------
// VW: qkv V-third blocks also write transposed vT. C2D: 2-D XCD chunk.
template<int BN, bool GELU, typename OT, bool VW = false, bool C2D = false>
__global__ __launch_bounds__(512) void gemm_pl(const u16* __restrict__ A,
                                               const u16* __restrict__ BT,
                                               const float* __restrict__ bias,
                                               OT* __restrict__ C,
                                               u16* __restrict__ vTout,
                                               int M, int N, int K, int ldc) {
    constexpr int NF = BN / 64;
    constexpr int BNI = BN / 64;
    constexpr int LTOT = 2 + BNI;
    __shared__ u16 As[2][128 * 64];
    __shared__ u16 Bs[2][BN * 64];

    int t = threadIdx.x;
    int w = t >> 6, l = t & 63, l16 = l & 15, lh = l >> 4;
    int wr = w >> 2, wc = w & 3;

    int nbm = M >> 7;
    int id = blockIdx.x;
    size_t m0, n0;
    if constexpr (C2D) {
        int x = id & 7, j = id >> 3;
        int ntn2 = (int)(gridDim.x >> 6);
        int mi = (x & 3) * 8 + (j & 7);
        int ni = (x >> 2) * ntn2 + (j >> 3);
        m0 = (size_t)mi * 128;
        n0 = (size_t)ni * BN;
    } else {
        int cpx = gridDim.x >> 3;
        int id2 = (id & 7) * cpx + (id >> 3);
        m0 = (size_t)(id2 % nbm) * 128;
        n0 = (size_t)(id2 / nbm) * BN;
    }

    int rowA = t >> 3;
    int gc2 = (t & 7) ^ (rowA & 7);
    const u16* Ag = A + (m0 + rowA) * (size_t)K + gc2 * 8;
    const u16* Bg = BT + (n0 + rowA) * (size_t)K + gc2 * 8;
    int wb = w * 512;

    f32x4 acc[4][NF] = {};
    int rx = (l16 & 7) * 8;

    #pragma unroll
    for (int j = 0; j < 2; ++j)
        gld_lds16(Ag + (size_t)j * 64 * K, &As[0][j * 4096 + wb]);
    #pragma unroll
    for (int j = 0; j < BNI; ++j)
        gld_lds16(Bg + (size_t)j * 64 * K, &Bs[0][j * 4096 + wb]);
    #pragma unroll
    for (int j = 0; j < 2; ++j)
        gld_lds16(Ag + 64 + (size_t)j * 64 * K, &As[1][j * 4096 + wb]);
    #pragma unroll
    for (int j = 0; j < BNI; ++j)
        gld_lds16(Bg + 64 + (size_t)j * 64 * K, &Bs[1][j * 4096 + wb]);

#define GTILE(CB, kk, LAST)                                                   \
    {                                                                         \
        if (LAST) asm volatile("s_waitcnt vmcnt(0)" ::: "memory");            \
        else      asm volatile("s_waitcnt vmcnt(%0)" :: "n"(LTOT) : "memory");\
        hard_barrier();                                                       \
        __builtin_amdgcn_s_setprio(1);                                        \
        _Pragma("unroll")                                                     \
        for (int ks = 0; ks < 2; ++ks) {                                      \
            s16x8 af[4], bf[NF];                                              \
            _Pragma("unroll")                                                 \
            for (int fm = 0; fm < 4; ++fm) {                                  \
                int row = wr * 64 + fm * 16 + l16;                            \
                int col = ((ks * 4 + lh) * 8) ^ rx;                           \
                af[fm] = *(const s16x8*)&As[CB][row * 64 + col];              \
            }                                                                 \
            _Pragma("unroll")                                                 \
            for (int fn = 0; fn < NF; ++fn) {                                 \
                int row = wc * (BN / 4) + fn * 16 + l16;                      \
                int col = ((ks * 4 + lh) * 8) ^ rx;                           \
                bf[fn] = *(const s16x8*)&Bs[CB][row * 64 + col];              \
            }                                                                 \
            _Pragma("unroll")                                                 \
            for (int fm = 0; fm < 4; ++fm)                                    \
                _Pragma("unroll")                                             \
                for (int fn = 0; fn < NF; ++fn)                               \
                    acc[fm][fn] = mfma16(af[fm], bf[fn], acc[fm][fn]);        \
        }                                                                     \
        __builtin_amdgcn_s_setprio(0);                                        \
        hard_barrier();                                                       \
        if ((kk) + 128 < K) {                                                 \
            const u16* Ap = Ag + (kk) + 128;                                  \
            _Pragma("unroll")                                                 \
            for (int j = 0; j < 2; ++j)                                       \
                gld_lds16(Ap + (size_t)j * 64 * K, &As[CB][j * 4096 + wb]);   \
            const u16* Bp = Bg + (kk) + 128;                                  \
            _Pragma("unroll")                                                 \
            for (int j = 0; j < BNI; ++j)                                     \
                gld_lds16(Bp + (size_t)j * 64 * K, &Bs[CB][j * 4096 + wb]);   \
        }                                                                     \
    }

    for (int k0 = 0; k0 < K; k0 += 128) {
        GTILE(0, k0, (k0 + 64 >= K))
        GTILE(1, k0 + 64, (k0 + 128 >= K))
    }
#undef GTILE

    #pragma unroll
    for (int fn = 0; fn < NF; ++fn) {
        size_t col = n0 + wc * (BN / 4) + fn * 16 + l16;
        float bs = bias[col];
        #pragma unroll
        for (int fm = 0; fm < 4; ++fm) {
            size_t row0 = m0 + wr * 64 + fm * 16 + lh * 4;
            u16x4 pack;
            #pragma unroll
            for (int i = 0; i < 4; ++i) {
                float v = acc[fm][fn][i] + bs;
                if constexpr (GELU) {
                    float x3 = v * v * v;
                    v = 0.5f * v * (1.f + tanhf(0.7978845608f * (v + 0.044715f * x3)));
                }
                if constexpr (std::is_same<OT, u16>::value) {
                    u16 q = f2b(v);
                    C[(row0 + i) * ldc + col] = q;
                    pack[i] = q;
                } else {
                    C[(row0 + i) * ldc + col] = v;
                }
            }
            if constexpr (VW) {
                if (n0 >= 2048) {      // V third (block-uniform)
                    int hh = ((int)col - 2048) >> 6;
                    int dd = ((int)col - 2048) & 63;
                    size_t vrow = (size_t)(((row0 >> 11) * 16 + hh) * 64 + dd);
                    *(u16x4*)(vTout + vrow * 2048 + (row0 & 2047)) = pack;
                }
            }
        }
    }
}

// ---- MFMA GEMM, 3-buffer 2-deep counted-vmcnt, BN=64 (aproj/mproj) ---------
template<bool GELU, typename OT>
__global__ __launch_bounds__(512) void gemm_pl3(const u16* __restrict__ A,
                                                const u16* __restrict__ BT,
                                                const float* __restrict__ bias,
                                                OT* __restrict__ C,
                                                int M, int N, int K, int ldc) {
    __shared__ u16 As[3][128 * 64];
    __shared__ u16 Bs[3][64 * 64];

    int t = threadIdx.x;
    int w = t >> 6, l = t & 63, l16 = l & 15, lh = l >> 4;
    int wr = w >> 2, wc = w & 3;

    int id = blockIdx.x;
    int x = id & 7, j = id >> 3;                 // j in 0..63
    int mi = (x & 3) * 8 + (j & 7);              // 0..31
    int ni = (x >> 2) * 8 + (j >> 3);            // 0..15
    size_t m0 = (size_t)mi * 128;
    size_t n0 = (size_t)ni * 64;

    int rowA = t >> 3;
    int gc2 = (t & 7) ^ (rowA & 7);
    const u16* Ag = A + (m0 + rowA) * (size_t)K + gc2 * 8;
    const u16* Bg = BT + (n0 + rowA) * (size_t)K + gc2 * 8;
    int wb = w * 512;

    f32x4 acc[4] = {};
    int rx = (l16 & 7) * 8;

#define STAGE3(KK, BUF)                                                       \
    {                                                                         \
        gld_lds16(Ag + (KK), &As[BUF][wb]);                                   \
        gld_lds16(Ag + (KK) + (size_t)64 * K, &As[BUF][4096 + wb]);           \
        gld_lds16(Bg + (KK), &Bs[BUF][wb]);                                   \
    }

    int NT = K >> 6;
    STAGE3(0, 0)
    STAGE3(64, 1)
    if (NT > 2) STAGE3(128, 2)

    int cur = 0;
    #pragma unroll 1
    for (int kt = 0; kt < NT; ++kt) {
        if (kt + 2 < NT)      asm volatile("s_waitcnt vmcnt(6)" ::: "memory");
        else if (kt + 1 < NT) asm volatile("s_waitcnt vmcnt(3)" ::: "memory");
        else                  asm volatile("s_waitcnt vmcnt(0)" ::: "memory");
        hard_barrier();

        __builtin_amdgcn_s_setprio(1);
        #pragma unroll
        for (int ks = 0; ks < 2; ++ks) {
            s16x8 af[4], bf;
            #pragma unroll
            for (int fm = 0; fm < 4; ++fm) {
                int row = wr * 64 + fm * 16 + l16;
                int col = ((ks * 4 + lh) * 8) ^ rx;
                af[fm] = *(const s16x8*)&As[cur][row * 64 + col];
            }
            {
                int row = wc * 16 + l16;
                int col = ((ks * 4 + lh) * 8) ^ rx;
                bf = *(const s16x8*)&Bs[cur][row * 64 + col];
            }
            #pragma unroll
            for (int fm = 0; fm < 4; ++fm)
                acc[fm] = mfma16(af[fm], bf, acc[fm]);
        }
        __builtin_amdgcn_s_setprio(0);
        hard_barrier();

        if (kt + 3 < NT) STAGE3((size_t)(kt + 3) * 64, cur)
        cur = (cur == 2) ? 0 : cur + 1;
    }
#undef STAGE3

    size_t col = n0 + wc * 16 + l16;
    float bs = bias[col];
    #pragma unroll
    for (int fm = 0; fm < 4; ++fm) {
        size_t row0 = m0 + wr * 64 + fm * 16 + lh * 4;
        #pragma unroll
        for (int i = 0; i < 4; ++i) {
            float v = acc[fm][i] + bs;
            if constexpr (GELU) {
                float x3 = v * v * v;
                v = 0.5f * v * (1.f + tanhf(0.7978845608f * (v + 0.044715f * x3)));
            }
            if constexpr (std::is_same<OT, u16>::value)
                C[(row0 + i) * ldc + col] = f2b(v);
            else
                C[(row0 + i) * ldc + col] = v;
        }
    }
}

// --------------------------- causal attention -------------------------------
__global__ __launch_bounds__(256) void attn_kernel(const u16* __restrict__ qkv,
                                                   const u16* __restrict__ vT,
                                                   u16* __restrict__ p0,
                                                   u16* __restrict__ p1,
                                                   u16* __restrict__ p2,
                                                   u16* __restrict__ p3,
                                                   float2* __restrict__ stats) {
    constexpr int S = 2048, D3 = 3072, Dm = 1024;
    __shared__ u16 Kl[2][64 * 64];
    __shared__ u16 Vt[2][64 * 64];

    int t = threadIdx.x;
    int w = t >> 6, l = t & 63;
    int l32 = l & 31, hi = l >> 5;
    int bid = blockIdx.x;
    int bh = (bid & 7) * 4 + ((bid >> 3) & 3);
    int rest = bid >> 5;                 // 0..31
    int quar = rest & 3;
    int pr = rest >> 2;                  // 0..7
    int b = bh >> 4, h = bh & 15;
    size_t base = (size_t)b * S * D3;

    u16* pout = quar == 0 ? p0 : (quar == 1 ? p1 : (quar == 2 ? p2 : p3));

    int rK0 = t >> 3, gK = t & 7;
    int rK1 = rK0 + 32;
    size_t koff0 = (size_t)rK0 * D3 + (size_t)((gK ^ (rK0 & 7)) * 8);
    size_t koff1 = (size_t)rK1 * D3 + (size_t)((gK ^ (rK1 & 7)) * 8);
    const u16* kbase = qkv + base + Dm + h * 64;
    size_t voff0 = (size_t)(bh * 64 + rK0) * 2048 + (size_t)((gK ^ (rK0 & 7)) * 8);
    size_t voff1 = (size_t)(bh * 64 + 32 + rK0) * 2048 + (size_t)((gK ^ (rK0 & 7)) * 8);

    constexpr float cexp = 0.18033688011112042f;   // 0.125 * log2(e)
    constexpr float THR = 64.0f;                    // defer-max threshold
    int xg = l32 & 7;

#define STAGE(SC, BUF)                                                        \
    {                                                                         \
        size_t ko_ = (size_t)(SC) * 64 * D3;                                  \
        int kvb_ = (SC) * 64;                                                 \
        gld_lds16(kbase + ko_ + koff0, &Kl[BUF][w * 512]);                    \
        gld_lds16(kbase + ko_ + koff1, &Kl[BUF][2048 + w * 512]);             \
        gld_lds16(vT + voff0 + kvb_, &Vt[BUF][w * 512]);                      \
        gld_lds16(vT + voff1 + kvb_, &Vt[BUF][2048 + w * 512]);               \
    }

    #pragma unroll 1
    for (int ph = 0; ph < 2; ++ph) {
        int qt = ph ? (15 - pr) : pr;
        int qb = qt * 128 + w * 32;
        int nst = 2 * (qt + 1);
        int c0 = (nst * quar) >> 2;
        int c1 = (nst * (quar + 1)) >> 2;

        f32x16 O0 = {}, O1 = {};
        float m = -1e30f, lr = 0.f;

        if (c0 < c1) {
            s16x8 qf[4];
            const u16* qp = qkv + base + (size_t)(qb + l32) * D3 + h * 64 + hi * 8;
            #pragma unroll
            for (int kk = 0; kk < 4; ++kk)
                qf[kk] = *(const s16x8*)(qp + kk * 16);

            STAGE(c0, 0)
            if (c0 + 1 < c1) STAGE(c0 + 1, 1)

            int cur = 0;
            #pragma unroll 1
            for (int sc = c0; sc < c1; ++sc) {
                if (sc + 1 < c1)
                    asm volatile("s_waitcnt vmcnt(4)" ::: "memory");
                else
                    asm volatile("s_waitcnt vmcnt(0)" ::: "memory");
                hard_barrier();

                int kvb = sc * 64;
                int navail = ((qb - kvb) >> 5) + 1;
                if (navail > 0) {
                    if (navail > 2) navail = 2;
                    const u16* Kc = Kl[cur];
                    const u16* Vc = Vt[cur];
                    f32x16 sa0 = {}, sa1 = {};
                    #pragma unroll
                    for (int kk = 0; kk < 4; ++kk) {
                        s16x8 kf = *(const s16x8*)&Kc[l32 * 64 + (((2 * kk + hi) ^ xg) * 8)];
                        sa0 = mfma32(kf, qf[kk], sa0);
                    }
                    if (navail == 2) {
                        #pragma unroll
                        for (int kk = 0; kk < 4; ++kk) {
                            s16x8 kf = *(const s16x8*)&Kc[(32 + l32) * 64 + (((2 * kk + hi) ^ xg) * 8)];
                            sa1 = mfma32(kf, qf[kk], sa1);
                        }
                    }
                    bool diag0 = (kvb == qb);
                    bool diag1 = (kvb + 32 == qb);
                    float p[32];
                    float mx = -1e30f;
                    if (diag0 | diag1) {             // wave-uniform branch
                        #pragma unroll
                        for (int reg = 0; reg < 16; ++reg) {
                            int kvloc = (reg & 3) + 8 * (reg >> 2) + 4 * hi;
                            float s0 = sa0[reg];
                            if (diag0 && kvloc > l32) s0 = -1e30f;
                            p[reg] = s0;
                            mx = fmaxf(mx, s0);
                        }
                        if (navail == 2) {
                            #pragma unroll
                            for (int reg = 0; reg < 16; ++reg) {
                                int kvloc = (reg & 3) + 8 * (reg >> 2) + 4 * hi;
                                float s1 = sa1[reg];
                                if (diag1 && kvloc > l32) s1 = -1e30f;
                                p[16 + reg] = s1;
                                mx = fmaxf(mx, s1);
                            }
                        }
                    } else {
                        #pragma unroll
                        for (int reg = 0; reg < 16; ++reg) {
                            p[reg] = sa0[reg];
                            mx = fmaxf(mx, sa0[reg]);
                        }
                        if (navail == 2) {
                            #pragma unroll
                            for (int reg = 0; reg < 16; ++reg) {
                                p[16 + reg] = sa1[reg];
                                mx = fmaxf(mx, sa1[reg]);
                            }
                        }
                    }
                    mx = fmaxf(mx, __shfl_xor(mx, 32));
                    if (!__all(mx <= m + THR)) {          // defer-max (T13)
                        float mn = fmaxf(m, mx);
                        float a_ = exp2f(cexp * (m - mn));
                        m = mn;
                        #pragma unroll
                        for (int reg = 0; reg < 16; ++reg) {
                            int src = (reg & 3) + 8 * (reg >> 2) + 4 * hi;
                            float aq = __shfl(a_, src);
                            O0[reg] *= aq;
                            O1[reg] *= aq;
                        }
                        lr *= a_;
                    }
                    float cm = cexp * m;
                    float rs = 0.f;
                    #pragma unroll
                    for (int reg = 0; reg < 16; ++reg) {
                        p[reg] = exp2f(fmaf(cexp, p[reg], -cm));
                        rs += p[reg];
                    }
                    if (navail == 2) {
                        #pragma unroll
                        for (int reg = 16; reg < 32; ++reg) {
                            p[reg] = exp2f(fmaf(cexp, p[reg], -cm));
                            rs += p[reg];
                        }
                    }
                    rs += __shfl_xor(rs, 32);
                    lr += rs;

                    #pragma unroll
                    for (int c = 0; c < 4; ++c) {
                        if (c < navail * 2) {
                            int pb = (c >> 1) * 16 + (c & 1) * 8;
                            int pk01 = cvtpk(p[pb + 0], p[pb + 1]);
                            int pk23 = cvtpk(p[pb + 2], p[pb + 3]);
                            int pk45 = cvtpk(p[pb + 4], p[pb + 5]);
                            int pk67 = cvtpk(p[pb + 6], p[pb + 7]);
                            int sx01 = __shfl_xor(pk01, 32);
                            int sx23 = __shfl_xor(pk23, 32);
                            int sx45 = __shfl_xor(pk45, 32);
                            int sx67 = __shfl_xor(pk67, 32);
                            union { int i[4]; s16x8 v; } u;
                            u.i[0] = hi ? sx45 : pk01;
                            u.i[1] = hi ? sx67 : pk23;
                            u.i[2] = hi ? pk45 : sx01;
                            u.i[3] = hi ? pk67 : sx23;
                            int go = ((c * 2 + hi) ^ xg) * 8;
                            s16x8 vb0 = *(const s16x8*)&Vc[l32 * 64 + go];
                            O0 = mfma32(u.v, vb0, O0);
                            s16x8 vb1 = *(const s16x8*)&Vc[(32 + l32) * 64 + go];
                            O1 = mfma32(u.v, vb1, O1);
                        }
                    }
                }

                hard_barrier();
                if (sc + 2 < c1) STAGE(sc + 2, cur)
                cur ^= 1;
            }
        }

        size_t obase = (size_t)b * S * 1024 + h * 64;
        #pragma unroll
        for (int reg = 0; reg < 16; ++reg) {
            int src = (reg & 3) + 8 * (reg >> 2) + 4 * hi;
            size_t row = obase + (size_t)(qb + src) * 1024;
            pout[row + l32] = f2b(O0[reg]);
            pout[row + 32 + l32] = f2b(O1[reg]);
        }
        if (hi == 0) {
            float2 st; st.x = m; st.y = lr;
            stats[quar * 65536 + ((b * 2048 + qb + l32) * 16 + h)] = st;
        }
    }
#undef STAGE
}

// --------------------- residual + LayerNorm (row = 1024) --------------------
template<bool WB>
__global__ __launch_bounds__(256) void resln(const float* __restrict__ xa,
                                             const float* __restrict__ xb2,
                                             const float* __restrict__ g,
                                             const float* __restrict__ be,
                                             float* __restrict__ outf,
                                             u16* __restrict__ outb) {
    __shared__ float r1[4], r2[4];
    d_resln<WB>(xa, xb2, g, be, outf, outb, blockIdx.x, threadIdx.x, r1, r2);
}

// ---------------------------------------------------------------------------
extern "C" void kernel_launch(void* const* d_in, const int* in_sizes, int n_in,
                              void* d_out, int out_size, void* d_ws, size_t ws_size,
                              hipStream_t stream) {
    (void)in_sizes; (void)n_in; (void)out_size; (void)ws_size;
    const float* x       = (const float*)d_in[0];
    const float* w_attn  = (const float*)d_in[1];
    const float* b_attn  = (const float*)d_in[2];
    const float* w_aproj = (const float*)d_in[3];
    const float* b_aproj = (const float*)d_in[4];
    const float* g1      = (const float*)d_in[5];
    const float* b1      = (const float*)d_in[6];
    const float* w_fc    = (const float*)d_in[7];
    const float* b_fc    = (const float*)d_in[8];
    const float* w_mproj = (const float*)d_in[9];
    const float* b_mproj = (const float*)d_in[10];
    const float* g2      = (const float*)d_in[11];
    const float* b2      = (const float*)d_in[12];
    float* out = (float*)d_out;

    constexpr int M = 4096;           // B*S
    constexpr int D = 1024;

    char* ws = (char*)d_ws;
    u16*   slotA = (u16*)ws;                         // 32 MiB: qkv(24)+vT(8) -> h
    char*  pB    = ws + (32u << 20);                 //  8 MiB: xb -> part0/abuf -> nb
    char*  pC    = ws + (40u << 20);                 //  8 MiB: part1 -> wT(attn/fc/mproj)
    char*  pD    = ws + (48u << 20);                 // 16 MiB: part2+part3 -> aout -> mout
    char*  pE    = ws + (64u << 20);                 // 16 MiB: stats(2M)+wTa(@8M) -> nbuf

    u16*   xb    = (u16*)pB;
    u16*   wT    = (u16*)pC;
    u16*   qkv   = slotA;
    u16*   vT    = slotA + (24u << 20) / 2;          // 8 MiB region after qkv
    u16*   part0 = (u16*)pB;                         // becomes merged abuf
    u16*   part1 = (u16*)pC;
    u16*   part2 = (u16*)pD;
    u16*   part3 = (u16*)(pD + (8u << 20));
    float2* stat = (float2*)pE;
    u16*   wTa   = (u16*)(pE + (8u << 20));          // aproj weight^T (2 MiB)
    u16*   abuf  = (u16*)pB;
    float* aout  = (float*)pD;
    float* nbuf  = (float*)pE;
    u16*   nb    = (u16*)pB;
    u16*   h     = slotA;
    float* mout  = (float*)pD;

    dim3 blk(256);
    dim3 blk512(512);

    // cvt x->bf16 || transpose w_attn
    fused_pre<<<dim3(4096 + 3072), blk, 0, stream>>>(x, xb, w_attn, wT);

    gemm_pl<128, false, u16, true, true><<<dim3((M / 128) * (3072 / 128)), blk512, 0, stream>>>(
        xb, wT, b_attn, qkv, vT, M, 3072, 1024, 3072);

    attn_kernel<<<dim3(1024), blk, 0, stream>>>(qkv, vT, part0, part1, part2, part3, stat);

    // merge partials || transpose w_aproj (into pE+8M — pC still holds part1)
    fused_mid<<<dim3(1024 + 1024), blk, 0, stream>>>(part0, part1, part2, part3,
                                                     stat, w_aproj, wTa);

    gemm_pl3<false, float><<<dim3((M / 128) * (1024 / 64)), blk512, 0, stream>>>(
        abuf, wTa, b_aproj, aout, M, 1024, 1024, 1024);

    // n = LN(x+aout) || transpose w_fc (pC free after merge consumed part1)
    fused_ln1<<<dim3(4096 + 4096), blk, 0, stream>>>(x, aout, g1, b1, nbuf, nb,
                                                     w_fc, wT);

    gemm_pl<128, true, u16, false, true><<<dim3((M / 128) * (4096 / 128)), blk512, 0, stream>>>(
        nb, wT, b_fc, h, nullptr, M, 4096, 1024, 4096);

    transpose_bf16<<<dim3(1024 / 32, 4096 / 32), blk, 0, stream>>>(w_mproj, wT, 4096, 1024);
    gemm_pl3<false, float><<<dim3((M / 128) * (1024 / 64)), blk512, 0, stream>>>(
        h, wT, b_mproj, mout, M, 1024, 4096, 1024);

    resln<false><<<dim3(M), blk, 0, stream>>>(nbuf, mout, g2, b2, out, nullptr);
}